// Round 2
// 1688.235 us; speedup vs baseline: 1.0854x; 1.0854x over previous
//
#include <hip/hip_runtime.h>

typedef unsigned short u16x8 __attribute__((ext_vector_type(8)));
typedef char i8x16 __attribute__((ext_vector_type(16)));
typedef int i32x4 __attribute__((ext_vector_type(4)));

constexpr int NN = 50000;   // nodes
constexpr int NG = 64;      // graphs
constexpr int MP = 50048;   // nodes padded to 128 (391*128)
constexpr int D0 = 900;     // input feature dim
constexpr int K0 = 960;     // conv1 half-K padded to 64
constexpr int D1 = 1024;    // conv1 out dim / conv2 half-K
constexpr int D2 = 2048;    // conv2 out dim
constexpr int KC1 = 2 * K0; // conv1 concatenated K = 1920
constexpr int KC2 = 2 * D1; // conv2 concatenated K = 2048

__device__ __forceinline__ float bf2f(unsigned short u) {
  return __uint_as_float(((unsigned)u) << 16);
}
__device__ __forceinline__ unsigned short f2bf(float f) {
  unsigned x = __float_as_uint(f);
  return (unsigned short)((x + 0x7fffu + ((x >> 16) & 1u)) >> 16);
}

__device__ __forceinline__ void gl_lds16(const void* g, void* l) {
  __builtin_amdgcn_global_load_lds((const __attribute__((address_space(1))) void*)g,
                                   (__attribute__((address_space(3))) void*)l, 16, 0, 0);
}

// ------- x: fp32 -> int8 into x-half of cat1, per-row scale -------
__global__ __launch_bounds__(256) void cvt_x(const float* __restrict__ in,
                                             char* __restrict__ cat1,
                                             float* __restrict__ xscale) {
  int r = blockIdx.x;
  __shared__ float row[K0];
  __shared__ float smax[256];
  int t = threadIdx.x;
  float m = 0.f;
  for (int c = t; c < K0; c += 256) {
    float v = (r < NN && c < D0) ? in[(size_t)r * D0 + c] : 0.f;
    row[c] = v;
    m = fmaxf(m, fabsf(v));
  }
  smax[t] = m;
  __syncthreads();
  for (int dd = 128; dd; dd >>= 1) {
    if (t < dd) smax[t] = fmaxf(smax[t], smax[t + dd]);
    __syncthreads();
  }
  float mx = smax[0];
  float inv = mx > 0.f ? 127.f / mx : 0.f;
  char* dst = cat1 + (size_t)r * KC1 + K0;  // x goes in second half
  for (int c = t; c < K0; c += 256) dst[c] = (char)(int)rintf(row[c] * inv);
  if (t == 0) xscale[r] = mx * (1.f / 127.f);
}

// ------- weights: [Wl | Wr] -> int8 cat with shared per-out-row scale -------
__global__ __launch_bounds__(256) void wq_cat(const float* __restrict__ Wl,
                                              const float* __restrict__ Wr, int Cin, int KH,
                                              char* __restrict__ q, float* __restrict__ sc) {
  int r = blockIdx.x, t = threadIdx.x;
  __shared__ float smax[256];
  float m = 0.f;
  for (int c = t; c < Cin; c += 256) {
    m = fmaxf(m, fabsf(Wl[(size_t)r * Cin + c]));
    m = fmaxf(m, fabsf(Wr[(size_t)r * Cin + c]));
  }
  smax[t] = m;
  __syncthreads();
  for (int dd = 128; dd; dd >>= 1) {
    if (t < dd) smax[t] = fmaxf(smax[t], smax[t + dd]);
    __syncthreads();
  }
  float mx = smax[0];
  float inv = mx > 0.f ? 127.f / mx : 0.f;
  char* row = q + (size_t)r * 2 * KH;
  for (int c = t; c < KH; c += 256) {
    row[c]      = (c < Cin) ? (char)(int)rintf(Wl[(size_t)r * Cin + c] * inv) : 0;
    row[KH + c] = (c < Cin) ? (char)(int)rintf(Wr[(size_t)r * Cin + c] * inv) : 0;
  }
  if (t == 0) sc[r] = mx * (1.f / 127.f);
}

// ------- h1 bf16 rows -> int8 into h1-half of cat2, per-row scale -------
__global__ __launch_bounds__(256) void quant_rows(const unsigned short* __restrict__ in,
                                                  char* __restrict__ cat2,
                                                  float* __restrict__ scale) {
  int r = blockIdx.x;
  __shared__ float row[D1];
  __shared__ float smax[256];
  int t = threadIdx.x;
  float m = 0.f;
  for (int c = t; c < D1; c += 256) {
    float v = bf2f(in[(size_t)r * D1 + c]);
    row[c] = v;
    m = fmaxf(m, fabsf(v));
  }
  smax[t] = m;
  __syncthreads();
  for (int dd = 128; dd; dd >>= 1) {
    if (t < dd) smax[t] = fmaxf(smax[t], smax[t + dd]);
    __syncthreads();
  }
  float mx = smax[0];
  float inv = mx > 0.f ? 127.f / mx : 0.f;
  char* dst = cat2 + (size_t)r * KC2 + D1;  // h1 goes in second half
  for (int c = t; c < D1; c += 256) dst[c] = (char)(int)rintf(row[c] * inv);
  if (t == 0) scale[r] = mx * (1.f / 127.f);
}

// ---------------- CSR build ----------------
__global__ void zero_i(int* p, int n) {
  int i = blockIdx.x * blockDim.x + threadIdx.x;
  if (i < n) p[i] = 0;
}
__global__ void count_k(const int* __restrict__ dst, int* __restrict__ deg, int E, int n) {
  int e = blockIdx.x * blockDim.x + threadIdx.x;
  if (e < E) {
    int d = dst[e];
    if ((unsigned)d < (unsigned)n) atomicAdd(&deg[d], 1);
  }
}
// hierarchical scan: block-local -> block sums -> add offsets
__global__ void scan1_k(const int* __restrict__ deg, int* __restrict__ off,
                        int* __restrict__ bsum, int n) {
  __shared__ int s[256];
  int t = threadIdx.x;
  int gid = blockIdx.x * 256 + t;
  int v = (gid < n) ? deg[gid] : 0;
  s[t] = v;
  __syncthreads();
  for (int d = 1; d < 256; d <<= 1) {
    int x = (t >= d) ? s[t - d] : 0;
    __syncthreads();
    s[t] += x;
    __syncthreads();
  }
  if (gid < n) off[gid] = s[t] - v;
  if (t == 255) bsum[blockIdx.x] = s[255];
}
__global__ void scan2_k(int* __restrict__ bsum, int nb) {
  __shared__ int s[256];
  int t = threadIdx.x;
  int v = (t < nb) ? bsum[t] : 0;
  s[t] = v;
  __syncthreads();
  for (int d = 1; d < 256; d <<= 1) {
    int x = (t >= d) ? s[t - d] : 0;
    __syncthreads();
    s[t] += x;
    __syncthreads();
  }
  if (t < nb) bsum[t] = s[t] - v;
  if (t == 255) bsum[nb] = s[255];
}
__global__ void scan3_k(int* __restrict__ off, const int* __restrict__ bsum, int n, int nb) {
  int gid = blockIdx.x * 256 + threadIdx.x;
  if (gid < n) off[gid] += bsum[gid >> 8];
  if (gid == 0) off[n] = bsum[nb];
}
__global__ void copy_i(const int* a, int* b, int n) {
  int i = blockIdx.x * blockDim.x + threadIdx.x;
  if (i < n) b[i] = a[i];
}
__global__ void fill_k(const int* __restrict__ src, const int* __restrict__ dst,
                       int* __restrict__ cursor, int* __restrict__ csr, int E, int n) {
  int e = blockIdx.x * blockDim.x + threadIdx.x;
  if (e < E) {
    int d = dst[e];
    if ((unsigned)d < (unsigned)n) {
      int p = atomicAdd(&cursor[d], 1);
      int s = src[e];
      if ((unsigned)s >= (unsigned)n) s = 0;
      csr[p] = s;
    }
  }
}

// ------- mean aggregation: one wave per node, int8 gather, int8 out -------
// Gathers the second-half (feature) columns of cat, writes quantized mean into
// the first-half columns, reusing the row's precomputed scale (clamped).
template <int K, int STRIDE>
__global__ __launch_bounds__(256) void agg_mean_i8w(char* __restrict__ cat,
                                                    const float* __restrict__ rscale,
                                                    const int* __restrict__ off,
                                                    const int* __restrict__ csr) {
  const int node = blockIdx.x * 4 + (threadIdx.x >> 6);
  const int lane = threadIdx.x & 63;
  const int d = lane * 16;
  const bool act = (d < K);
  const int e0 = off[node], e1 = off[node + 1];
  float a[16];
#pragma unroll
  for (int k = 0; k < 16; ++k) a[k] = 0.f;
  if (act) {
    const char* fp = cat + (size_t)K + d;  // feature half base + lane offset
    int e = e0;
    for (; e + 7 < e1; e += 8) {
      int s0 = csr[e],     s1 = csr[e + 1], s2 = csr[e + 2], s3 = csr[e + 3];
      int s4 = csr[e + 4], s5 = csr[e + 5], s6 = csr[e + 6], s7 = csr[e + 7];
      i8x16 v0 = *(const i8x16*)(fp + (size_t)s0 * STRIDE);
      i8x16 v1 = *(const i8x16*)(fp + (size_t)s1 * STRIDE);
      i8x16 v2 = *(const i8x16*)(fp + (size_t)s2 * STRIDE);
      i8x16 v3 = *(const i8x16*)(fp + (size_t)s3 * STRIDE);
      i8x16 v4 = *(const i8x16*)(fp + (size_t)s4 * STRIDE);
      i8x16 v5 = *(const i8x16*)(fp + (size_t)s5 * STRIDE);
      i8x16 v6 = *(const i8x16*)(fp + (size_t)s6 * STRIDE);
      i8x16 v7 = *(const i8x16*)(fp + (size_t)s7 * STRIDE);
      float c0 = rscale[s0], c1 = rscale[s1], c2 = rscale[s2], c3 = rscale[s3];
      float c4 = rscale[s4], c5 = rscale[s5], c6 = rscale[s6], c7 = rscale[s7];
#pragma unroll
      for (int k = 0; k < 16; ++k) {
        a[k] += c0 * (float)v0[k] + c1 * (float)v1[k] + c2 * (float)v2[k] + c3 * (float)v3[k];
        a[k] += c4 * (float)v4[k] + c5 * (float)v5[k] + c6 * (float)v6[k] + c7 * (float)v7[k];
      }
    }
    for (; e < e1; ++e) {
      int s = csr[e];
      float c = rscale[s];
      i8x16 v = *(const i8x16*)(fp + (size_t)s * STRIDE);
#pragma unroll
      for (int k = 0; k < 16; ++k) a[k] += c * (float)v[k];
    }
  }
  if (act) {
    int deg = e1 - e0;
    float inv = 1.f / (float)(deg > 1 ? deg : 1);
    float sc = rscale[node];
    float qi = sc > 0.f ? 1.f / sc : 0.f;  // quantize mean with row's own scale
    i8x16 q;
#pragma unroll
    for (int k = 0; k < 16; ++k) {
      float m = a[k] * inv * qi;
      m = fminf(fmaxf(rintf(m), -127.f), 127.f);
      q[k] = (char)(int)m;
    }
    *(i8x16*)&cat[(size_t)node * STRIDE + d] = q;  // mean half
  }
}

// ---------------- single-pass K-concatenated int8 MFMA GEMM ----------------
// C[m,n] = relu?( sA(m)*sW(n)*sum_k A[m,k]W[n,k] + bias[n] ), bf16 out.
// 128x128 tile, 4 waves 64x64, mfma_i32_16x16x64_i8, global_load_lds staging.
// XCD-aware bijective block swizzle (y-major chunks) keeps the N-blocks that
// share an A-tile on one XCD's L2. Epilogue stages C through LDS and stores
// full 256B row segments (dwordx4) to avoid partial-line RMW.
template <int KP, int N, bool RELU>
__global__ __launch_bounds__(256, 5) void gemm_i8(const char* __restrict__ A,
                                                  const char* __restrict__ W,
                                                  const float* __restrict__ sA_,
                                                  const float* __restrict__ sW_,
                                                  const float* __restrict__ bias,
                                                  unsigned short* __restrict__ C) {
  __shared__ __align__(16) char smem[17408];
  char* sA = smem;
  char* sB = smem + 8192;
  float* sc0 = (float*)(smem + 16384);
  float* sc1 = sc0 + 128;

  // bijective XCD swizzle: each XCD gets a contiguous chunk of block ids,
  // x (N-dim) fastest inside the chunk -> A-tile reuse within one L2.
  const int gx = gridDim.x;
  const int nwg = gx * gridDim.y;
  const int flat = blockIdx.y * gx + blockIdx.x;
  int newid = flat;
  if ((nwg & 7) == 0) newid = (flat & 7) * (nwg >> 3) + (flat >> 3);
  const int bxi = newid % gx;
  const int byi = newid / gx;

  const int tid = threadIdx.x;
  const int wave = tid >> 6, lane = tid & 63;
  const int quad = lane >> 4, l16 = lane & 15;
  const int wm = (wave >> 1) * 64, wn = (wave & 1) * 64;
  const long long bm = (long long)byi * 128;
  const long long bn = (long long)bxi * 128;

  if (tid < 128) sc0[tid] = sA_[bm + tid];
  else sc1[tid - 128] = sW_[bn + tid - 128];

  const int srow = wave * 16 + (lane >> 2);
  const int skoff = (lane & 3) * 16;
  char* lA = &sA[wave * 1024 + lane * 16];
  char* lB = &sB[wave * 1024 + lane * 16];
  const char* gA = A + (bm + srow) * (long long)KP + skoff;
  const char* gW = W + (bn + srow) * (long long)KP + skoff;

  i32x4 iacc[4][4];
#pragma unroll
  for (int i = 0; i < 4; ++i)
#pragma unroll
    for (int j = 0; j < 4; ++j) iacc[i][j] = (i32x4){0, 0, 0, 0};

#pragma unroll 1
  for (int k0 = 0; k0 < KP; k0 += 64) {
    __syncthreads();  // previous iteration's LDS reads complete
    gl_lds16(gA + k0, lA);
    gl_lds16(gA + k0 + (size_t)64 * KP, lA + 4096);
    gl_lds16(gW + k0, lB);
    gl_lds16(gW + k0 + (size_t)64 * KP, lB + 4096);
    __syncthreads();  // staging complete
    i32x4 af[4], bg[4];
#pragma unroll
    for (int i = 0; i < 4; ++i)
      af[i] = *(const i32x4*)&sA[(wm + 16 * i + l16) * 64 + quad * 16];
#pragma unroll
    for (int j = 0; j < 4; ++j)
      bg[j] = *(const i32x4*)&sB[(wn + 16 * j + l16) * 64 + quad * 16];
#pragma unroll
    for (int i = 0; i < 4; ++i)
#pragma unroll
      for (int j = 0; j < 4; ++j)
        iacc[i][j] = __builtin_amdgcn_mfma_i32_16x16x64_i8(af[i], bg[j], iacc[i][j], 0, 0, 0);
  }

  // ---- epilogue: preload scales/bias to regs, then reuse smem as C tile ----
  float rs[4][4], cs[4], bvj[4];
#pragma unroll
  for (int i = 0; i < 4; ++i)
#pragma unroll
    for (int r = 0; r < 4; ++r) rs[i][r] = sc0[wm + 16 * i + quad * 4 + r];
#pragma unroll
  for (int j = 0; j < 4; ++j) {
    const int coll = wn + 16 * j + l16;
    cs[j] = sc1[coll];
    bvj[j] = bias[bn + coll];
  }
  unsigned short* ct = (unsigned short*)smem;  // [64][136] u16 = 17408 B
  const int trow = tid >> 4;        // 0..15
  const int tcol = (tid & 15) * 8;  // u16 offset within row
#pragma unroll
  for (int p = 0; p < 2; ++p) {
    __syncthreads();  // p=0: main-loop reads + scale preload done; p=1: stores of pass0 done
    if ((wm >> 6) == p) {
#pragma unroll
      for (int i = 0; i < 4; ++i)
#pragma unroll
        for (int j = 0; j < 4; ++j)
#pragma unroll
          for (int r = 0; r < 4; ++r) {
            float v = (float)iacc[i][j][r] * rs[i][r] * cs[j] + bvj[j];
            if (RELU) v = fmaxf(v, 0.f);
            ct[(16 * i + quad * 4 + r) * 136 + wn + 16 * j + l16] = f2bf(v);
          }
    }
    __syncthreads();  // C half-tile staged
#pragma unroll
    for (int s = 0; s < 4; ++s) {
      const int rl = s * 16 + trow;
      i32x4 vv = *(const i32x4*)&ct[rl * 136 + tcol];
      *(i32x4*)&C[(bm + p * 64 + rl) * (long long)N + bn + tcol] = vv;
    }
  }
}

// ---------------- graph boundaries ----------------
__global__ void bounds_k(const int* __restrict__ batch, int* __restrict__ gstart, int n, int G) {
  int g = blockIdx.x * blockDim.x + threadIdx.x;
  if (g > G) return;
  int lo = 0, hi = n;
  while (lo < hi) {
    int mid = (lo + hi) >> 1;
    if (batch[mid] < g) lo = mid + 1; else hi = mid;
  }
  gstart[g] = lo;
}

// ---------------- segment max pool ----------------
__global__ void segmax_k(const unsigned short* __restrict__ h2b, const int* __restrict__ gstart,
                         float* __restrict__ pooled) {
  int g = blockIdx.x;
  int c = blockIdx.y * 256 + threadIdx.x;
  int i0 = gstart[g], i1 = gstart[g + 1];
  float m = -3.4e38f;
  for (int i = i0; i < i1; ++i) m = fmaxf(m, bf2f(h2b[(size_t)i * D2 + c]));
  if (i0 >= i1) m = 0.f;
  pooled[(size_t)g * D2 + c] = m;
}

// ---------------- MLP head (fp32) ----------------
__global__ void head1_k(const float* __restrict__ pooled, const float* __restrict__ Wf1,
                        const float* __restrict__ bf1, float* __restrict__ hid) {
  int g = blockIdx.x, chunk = blockIdx.y;
  __shared__ float sp[2048];
  for (int i = threadIdx.x; i < 2048; i += 256) sp[i] = pooled[(size_t)g * 2048 + i];
  __syncthreads();
  int wave = threadIdx.x >> 6, lane = threadIdx.x & 63;
  for (int oi = wave; oi < 64; oi += 4) {
    int o = chunk * 64 + oi;
    const float4* wr = (const float4*)&Wf1[(size_t)o * 2048];
    float s = 0.f;
    for (int c = lane; c < 512; c += 64) {
      float4 wv = wr[c];
      float4 pv = *(const float4*)&sp[c * 4];
      s += wv.x * pv.x + wv.y * pv.y + wv.z * pv.z + wv.w * pv.w;
    }
    for (int off = 32; off; off >>= 1) s += __shfl_down(s, off);
    if (lane == 0) hid[(size_t)g * 1024 + o] = fmaxf(s + bf1[o], 0.f);
  }
}
__global__ void head2_k(const float* __restrict__ hid, const float* __restrict__ Wf2,
                        const float* __restrict__ bf2, float* __restrict__ out) {
  int g = blockIdx.x, t = threadIdx.x;
  __shared__ float sh[1024];
  __shared__ float red[256];
  for (int i = t; i < 1024; i += 256) sh[i] = hid[(size_t)g * 1024 + i];
  __syncthreads();
  for (int o = 0; o < 6; ++o) {
    float s = 0.f;
    for (int k = t; k < 1024; k += 256) s += sh[k] * Wf2[o * 1024 + k];
    red[t] = s;
    __syncthreads();
    for (int d = 128; d; d >>= 1) {
      if (t < d) red[t] += red[t + d];
      __syncthreads();
    }
    if (t == 0) out[g * 6 + o] = red[0] + bf2[o];
    __syncthreads();
  }
}

extern "C" void kernel_launch(void* const* d_in, const int* in_sizes, int n_in,
                              void* d_out, int out_size, void* d_ws, size_t ws_size,
                              hipStream_t stream) {
  const float* x    = (const float*)d_in[0];
  const int* ei     = (const int*)d_in[1];
  const int* batch  = (const int*)d_in[2];
  const float* W1l  = (const float*)d_in[3];
  const float* b1   = (const float*)d_in[4];
  const float* W1r  = (const float*)d_in[5];
  const float* W2l  = (const float*)d_in[6];
  const float* b2   = (const float*)d_in[7];
  const float* W2r  = (const float*)d_in[8];
  const float* Wf1  = (const float*)d_in[9];
  const float* bf1  = (const float*)d_in[10];
  const float* Wf2  = (const float*)d_in[11];
  const float* bf2  = (const float*)d_in[12];
  float* out = (float*)d_out;

  const int E = in_sizes[1] / 2;
  const int* srcp = ei;
  const int* dstp = ei + E;
  const int NB = (MP + 255) / 256;  // scan blocks

  char* w = (char*)d_ws;
  auto take = [&](size_t b) {
    void* p = (void*)w;
    w += (b + 255) & ~(size_t)255;
    return p;
  };
  char* cat1      = (char*)take((size_t)MP * KC1);        // [mean | x] int8
  char* cat2      = (char*)take((size_t)MP * KC2);        // [mean2 | h1] int8
  unsigned short* h1b = (unsigned short*)take((size_t)MP * D1 * 2);
  unsigned short* h2b = (unsigned short*)take((size_t)MP * D2 * 2);
  char* wcat1     = (char*)take((size_t)D1 * KC1);
  char* wcat2     = (char*)take((size_t)D2 * KC2);
  float* xscale   = (float*)take((size_t)MP * 4);
  float* h1scale  = (float*)take((size_t)MP * 4);
  float* swc1     = (float*)take((size_t)D1 * 4);
  float* swc2     = (float*)take((size_t)D2 * 4);
  int* deg    = (int*)take((size_t)MP * 4);
  int* off    = (int*)take((size_t)(MP + 1) * 4);
  int* bsum   = (int*)take((size_t)(NB + 1) * 4);
  int* cursor = (int*)take((size_t)MP * 4);
  int* csr    = (int*)take((size_t)E * 4);
  int* gstart = (int*)take((size_t)(NG + 1) * 4);
  float* pooled = (float*)take((size_t)NG * D2 * 4);
  float* hid    = (float*)take((size_t)NG * 1024 * 4);

  cvt_x<<<MP, 256, 0, stream>>>(x, cat1, xscale);
  wq_cat<<<D1, 256, 0, stream>>>(W1l, W1r, D0, K0, wcat1, swc1);
  wq_cat<<<D2, 256, 0, stream>>>(W2l, W2r, D1, D1, wcat2, swc2);

  zero_i<<<(MP + 255) / 256, 256, 0, stream>>>(deg, MP);
  count_k<<<(E + 255) / 256, 256, 0, stream>>>(dstp, deg, E, NN);
  scan1_k<<<NB, 256, 0, stream>>>(deg, off, bsum, MP);
  scan2_k<<<1, 256, 0, stream>>>(bsum, NB);
  scan3_k<<<NB, 256, 0, stream>>>(off, bsum, MP, NB);
  copy_i<<<(MP + 255) / 256, 256, 0, stream>>>(off, cursor, MP);
  fill_k<<<(E + 255) / 256, 256, 0, stream>>>(srcp, dstp, cursor, csr, E, NN);

  // conv1: mean half of cat1 <- agg(x half); h1 = relu(cat1 @ wcat1^T + b1)
  agg_mean_i8w<K0, KC1><<<MP / 4, 256, 0, stream>>>(cat1, xscale, off, csr);
  gemm_i8<KC1, D1, true><<<dim3(D1 / 128, MP / 128), 256, 0, stream>>>(
      cat1, wcat1, xscale, swc1, b1, h1b);

  // conv2: quantize h1 into cat2; mean2 half <- agg(h1 half); h2 = cat2 @ wcat2^T + b2
  quant_rows<<<MP, 256, 0, stream>>>(h1b, cat2, h1scale);
  agg_mean_i8w<D1, KC2><<<MP / 4, 256, 0, stream>>>(cat2, h1scale, off, csr);
  gemm_i8<KC2, D2, false><<<dim3(D2 / 128, MP / 128), 256, 0, stream>>>(
      cat2, wcat2, h1scale, swc2, b2, h2b);

  bounds_k<<<1, 128, 0, stream>>>(batch, gstart, NN, NG);
  segmax_k<<<dim3(NG, D2 / 256), 256, 0, stream>>>(h2b, gstart, pooled);
  head1_k<<<dim3(NG, 16), 256, 0, stream>>>(pooled, Wf1, bf1, hid);
  head2_k<<<NG, 256, 0, stream>>>(hid, Wf2, bf2, out);
}

// Round 3
// 1666.399 us; speedup vs baseline: 1.0996x; 1.0131x over previous
//
#include <hip/hip_runtime.h>

typedef unsigned short u16x8 __attribute__((ext_vector_type(8)));
typedef char i8x16 __attribute__((ext_vector_type(16)));
typedef int i32x4 __attribute__((ext_vector_type(4)));

constexpr int NN = 50000;   // nodes
constexpr int NG = 64;      // graphs
constexpr int MP = 50048;   // nodes padded to 128 (391*128)
constexpr int D0 = 900;     // input feature dim
constexpr int K0 = 960;     // conv1 half-K padded to 64
constexpr int D1 = 1024;    // conv1 out dim / conv2 half-K
constexpr int D2 = 2048;    // conv2 out dim
constexpr int KC1 = 2 * K0; // conv1 concatenated K = 1920
constexpr int KC2 = 2 * D1; // conv2 concatenated K = 2048

__device__ __forceinline__ float bf2f(unsigned short u) {
  return __uint_as_float(((unsigned)u) << 16);
}
__device__ __forceinline__ unsigned short f2bf(float f) {
  unsigned x = __float_as_uint(f);
  return (unsigned short)((x + 0x7fffu + ((x >> 16) & 1u)) >> 16);
}

__device__ __forceinline__ void gl_lds16(const void* g, void* l) {
  __builtin_amdgcn_global_load_lds((const __attribute__((address_space(1))) void*)g,
                                   (__attribute__((address_space(3))) void*)l, 16, 0, 0);
}

// ------- x: fp32 -> int8 into x-half of cat1, per-row scale -------
__global__ __launch_bounds__(256) void cvt_x(const float* __restrict__ in,
                                             char* __restrict__ cat1,
                                             float* __restrict__ xscale) {
  int r = blockIdx.x;
  __shared__ float row[K0];
  __shared__ float smax[256];
  int t = threadIdx.x;
  float m = 0.f;
  for (int c = t; c < K0; c += 256) {
    float v = (r < NN && c < D0) ? in[(size_t)r * D0 + c] : 0.f;
    row[c] = v;
    m = fmaxf(m, fabsf(v));
  }
  smax[t] = m;
  __syncthreads();
  for (int dd = 128; dd; dd >>= 1) {
    if (t < dd) smax[t] = fmaxf(smax[t], smax[t + dd]);
    __syncthreads();
  }
  float mx = smax[0];
  float inv = mx > 0.f ? 127.f / mx : 0.f;
  char* dst = cat1 + (size_t)r * KC1 + K0;  // x goes in second half
  for (int c = t; c < K0; c += 256) dst[c] = (char)(int)rintf(row[c] * inv);
  if (t == 0) xscale[r] = mx * (1.f / 127.f);
}

// ------- weights: [Wl | Wr] -> int8 cat with shared per-out-row scale -------
__global__ __launch_bounds__(256) void wq_cat(const float* __restrict__ Wl,
                                              const float* __restrict__ Wr, int Cin, int KH,
                                              char* __restrict__ q, float* __restrict__ sc) {
  int r = blockIdx.x, t = threadIdx.x;
  __shared__ float smax[256];
  float m = 0.f;
  for (int c = t; c < Cin; c += 256) {
    m = fmaxf(m, fabsf(Wl[(size_t)r * Cin + c]));
    m = fmaxf(m, fabsf(Wr[(size_t)r * Cin + c]));
  }
  smax[t] = m;
  __syncthreads();
  for (int dd = 128; dd; dd >>= 1) {
    if (t < dd) smax[t] = fmaxf(smax[t], smax[t + dd]);
    __syncthreads();
  }
  float mx = smax[0];
  float inv = mx > 0.f ? 127.f / mx : 0.f;
  char* row = q + (size_t)r * 2 * KH;
  for (int c = t; c < KH; c += 256) {
    row[c]      = (c < Cin) ? (char)(int)rintf(Wl[(size_t)r * Cin + c] * inv) : 0;
    row[KH + c] = (c < Cin) ? (char)(int)rintf(Wr[(size_t)r * Cin + c] * inv) : 0;
  }
  if (t == 0) sc[r] = mx * (1.f / 127.f);
}

// ------- h1 bf16 rows -> int8 into h1-half of cat2, per-row scale -------
__global__ __launch_bounds__(256) void quant_rows(const unsigned short* __restrict__ in,
                                                  char* __restrict__ cat2,
                                                  float* __restrict__ scale) {
  int r = blockIdx.x;
  __shared__ float row[D1];
  __shared__ float smax[256];
  int t = threadIdx.x;
  float m = 0.f;
  for (int c = t; c < D1; c += 256) {
    float v = bf2f(in[(size_t)r * D1 + c]);
    row[c] = v;
    m = fmaxf(m, fabsf(v));
  }
  smax[t] = m;
  __syncthreads();
  for (int dd = 128; dd; dd >>= 1) {
    if (t < dd) smax[t] = fmaxf(smax[t], smax[t + dd]);
    __syncthreads();
  }
  float mx = smax[0];
  float inv = mx > 0.f ? 127.f / mx : 0.f;
  char* dst = cat2 + (size_t)r * KC2 + D1;  // h1 goes in second half
  for (int c = t; c < D1; c += 256) dst[c] = (char)(int)rintf(row[c] * inv);
  if (t == 0) scale[r] = mx * (1.f / 127.f);
}

// ---------------- CSR build ----------------
__global__ void zero_i(int* p, int n) {
  int i = blockIdx.x * blockDim.x + threadIdx.x;
  if (i < n) p[i] = 0;
}
__global__ void count_k(const int* __restrict__ dst, int* __restrict__ deg, int E, int n) {
  int e = blockIdx.x * blockDim.x + threadIdx.x;
  if (e < E) {
    int d = dst[e];
    if ((unsigned)d < (unsigned)n) atomicAdd(&deg[d], 1);
  }
}
// hierarchical scan: block-local -> block sums -> add offsets
__global__ void scan1_k(const int* __restrict__ deg, int* __restrict__ off,
                        int* __restrict__ bsum, int n) {
  __shared__ int s[256];
  int t = threadIdx.x;
  int gid = blockIdx.x * 256 + t;
  int v = (gid < n) ? deg[gid] : 0;
  s[t] = v;
  __syncthreads();
  for (int d = 1; d < 256; d <<= 1) {
    int x = (t >= d) ? s[t - d] : 0;
    __syncthreads();
    s[t] += x;
    __syncthreads();
  }
  if (gid < n) off[gid] = s[t] - v;
  if (t == 255) bsum[blockIdx.x] = s[255];
}
__global__ void scan2_k(int* __restrict__ bsum, int nb) {
  __shared__ int s[256];
  int t = threadIdx.x;
  int v = (t < nb) ? bsum[t] : 0;
  s[t] = v;
  __syncthreads();
  for (int d = 1; d < 256; d <<= 1) {
    int x = (t >= d) ? s[t - d] : 0;
    __syncthreads();
    s[t] += x;
    __syncthreads();
  }
  if (t < nb) bsum[t] = s[t] - v;
  if (t == 255) bsum[nb] = s[255];
}
__global__ void scan3_k(int* __restrict__ off, const int* __restrict__ bsum, int n, int nb) {
  int gid = blockIdx.x * 256 + threadIdx.x;
  if (gid < n) off[gid] += bsum[gid >> 8];
  if (gid == 0) off[n] = bsum[nb];
}
__global__ void copy_i(const int* a, int* b, int n) {
  int i = blockIdx.x * blockDim.x + threadIdx.x;
  if (i < n) b[i] = a[i];
}
__global__ void fill_k(const int* __restrict__ src, const int* __restrict__ dst,
                       int* __restrict__ cursor, int* __restrict__ csr, int E, int n) {
  int e = blockIdx.x * blockDim.x + threadIdx.x;
  if (e < E) {
    int d = dst[e];
    if ((unsigned)d < (unsigned)n) {
      int p = atomicAdd(&cursor[d], 1);
      int s = src[e];
      if ((unsigned)s >= (unsigned)n) s = 0;
      csr[p] = s;
    }
  }
}

// ------- mean aggregation: one wave per node, int8 gather, int8 out -------
template <int K, int STRIDE>
__global__ __launch_bounds__(256) void agg_mean_i8w(char* __restrict__ cat,
                                                    const float* __restrict__ rscale,
                                                    const int* __restrict__ off,
                                                    const int* __restrict__ csr) {
  const int node = blockIdx.x * 4 + (threadIdx.x >> 6);
  const int lane = threadIdx.x & 63;
  const int d = lane * 16;
  const bool act = (d < K);
  const int e0 = off[node], e1 = off[node + 1];
  float a[16];
#pragma unroll
  for (int k = 0; k < 16; ++k) a[k] = 0.f;
  if (act) {
    const char* fp = cat + (size_t)K + d;  // feature half base + lane offset
    int e = e0;
    for (; e + 7 < e1; e += 8) {
      int s0 = csr[e],     s1 = csr[e + 1], s2 = csr[e + 2], s3 = csr[e + 3];
      int s4 = csr[e + 4], s5 = csr[e + 5], s6 = csr[e + 6], s7 = csr[e + 7];
      i8x16 v0 = *(const i8x16*)(fp + (size_t)s0 * STRIDE);
      i8x16 v1 = *(const i8x16*)(fp + (size_t)s1 * STRIDE);
      i8x16 v2 = *(const i8x16*)(fp + (size_t)s2 * STRIDE);
      i8x16 v3 = *(const i8x16*)(fp + (size_t)s3 * STRIDE);
      i8x16 v4 = *(const i8x16*)(fp + (size_t)s4 * STRIDE);
      i8x16 v5 = *(const i8x16*)(fp + (size_t)s5 * STRIDE);
      i8x16 v6 = *(const i8x16*)(fp + (size_t)s6 * STRIDE);
      i8x16 v7 = *(const i8x16*)(fp + (size_t)s7 * STRIDE);
      float c0 = rscale[s0], c1 = rscale[s1], c2 = rscale[s2], c3 = rscale[s3];
      float c4 = rscale[s4], c5 = rscale[s5], c6 = rscale[s6], c7 = rscale[s7];
#pragma unroll
      for (int k = 0; k < 16; ++k) {
        a[k] += c0 * (float)v0[k] + c1 * (float)v1[k] + c2 * (float)v2[k] + c3 * (float)v3[k];
        a[k] += c4 * (float)v4[k] + c5 * (float)v5[k] + c6 * (float)v6[k] + c7 * (float)v7[k];
      }
    }
    for (; e < e1; ++e) {
      int s = csr[e];
      float c = rscale[s];
      i8x16 v = *(const i8x16*)(fp + (size_t)s * STRIDE);
#pragma unroll
      for (int k = 0; k < 16; ++k) a[k] += c * (float)v[k];
    }
  }
  if (act) {
    int deg = e1 - e0;
    float inv = 1.f / (float)(deg > 1 ? deg : 1);
    float sc = rscale[node];
    float qi = sc > 0.f ? 1.f / sc : 0.f;  // quantize mean with row's own scale
    i8x16 q;
#pragma unroll
    for (int k = 0; k < 16; ++k) {
      float m = a[k] * inv * qi;
      m = fminf(fmaxf(rintf(m), -127.f), 127.f);
      q[k] = (char)(int)m;
    }
    *(i8x16*)&cat[(size_t)node * STRIDE + d] = q;  // mean half
  }
}

// ---------------- single-pass K-concatenated int8 MFMA GEMM ----------------
// C[m,n] = relu?( sA(m)*sW(n)*sum_k A[m,k]W[n,k] + bias[n] ), bf16 out.
// 128x128 tile, 4 waves 64x64, mfma_i32_16x16x64_i8.
// T1: bijective XCD block swizzle (A-panel reuse within one L2).
// T3+T4: double-buffered LDS + counted s_waitcnt vmcnt(4) across raw s_barrier
//        (next tile's global_load_lds stays in flight during MFMA).
// T2: conflict-free LDS read swizzle via pre-swizzled GLOBAL source chunk
//     (LDS dest stays linear for global_load_lds; rule both-sides-or-neither):
//     stored slot = chunk ^ ((row>>1)&3); granule(lane) = 4*(r&1)|slot covers
//     all 8 LDS 16B-granules per 8 consecutive lanes.
// T5: s_setprio(1) around the MFMA cluster.
// Epilogue stages C through LDS and stores full 256B row segments (no RMW).
template <int KP, int N, bool RELU>
__global__ __launch_bounds__(256, 4) void gemm_i8(const char* __restrict__ A,
                                                  const char* __restrict__ W,
                                                  const float* __restrict__ sA_,
                                                  const float* __restrict__ sW_,
                                                  const float* __restrict__ bias,
                                                  unsigned short* __restrict__ C) {
  // [2][ A:8192 | B:8192 ] double buffer + 1KB scales
  __shared__ __align__(16) char smem[33792];
  float* sc0 = (float*)(smem + 32768);
  float* sc1 = sc0 + 128;

  // bijective XCD swizzle: each XCD gets a contiguous chunk of block ids,
  // x (N-dim) fastest inside the chunk -> A-tile reuse within one L2.
  const int gx = gridDim.x;
  const int nwg = gx * gridDim.y;
  const int flat = blockIdx.y * gx + blockIdx.x;
  int newid = flat;
  if ((nwg & 7) == 0) newid = (flat & 7) * (nwg >> 3) + (flat >> 3);
  const int bxi = newid % gx;
  const int byi = newid / gx;

  const int tid = threadIdx.x;
  const int wave = tid >> 6, lane = tid & 63;
  const int quad = lane >> 4, l16 = lane & 15;
  const int wm = (wave >> 1) * 64, wn = (wave & 1) * 64;
  const long long bm = (long long)byi * 128;
  const long long bn = (long long)bxi * 128;

  if (tid < 128) sc0[tid] = sA_[bm + tid];
  else sc1[tid - 128] = sW_[bn + tid - 128];

  // staging: wave w, lane l covers tile row 16w+(l>>2) (and +64), slot l&3.
  // pre-swizzled global chunk: c = (l&3) ^ ((l>>3)&3)  (= slot ^ ((row>>1)&3))
  const int srow = wave * 16 + (lane >> 2);
  const int cswz = (lane & 3) ^ ((lane >> 3) & 3);
  const int ldst = wave * 1024 + lane * 16;
  const char* gA = A + (bm + srow) * (long long)KP + cswz * 16;
  const char* gW = W + (bn + srow) * (long long)KP + cswz * 16;

  // fragment-read offset: row stride 64, slot = quad ^ ((l16>>1)&3)
  const int rdoff = l16 * 64 + ((quad ^ ((l16 >> 1) & 3)) << 4);

  i32x4 iacc[4][4];
#pragma unroll
  for (int i = 0; i < 4; ++i)
#pragma unroll
    for (int j = 0; j < 4; ++j) iacc[i][j] = (i32x4){0, 0, 0, 0};

  constexpr int NT = KP / 64;

  // prologue: stage tile 0 into buffer 0
  {
    char* dA = smem + ldst;
    gl_lds16(gA, dA);
    gl_lds16(gA + (size_t)64 * KP, dA + 4096);
    gl_lds16(gW, dA + 8192);
    gl_lds16(gW + (size_t)64 * KP, dA + 12288);
  }

#pragma unroll 1
  for (int t = 0; t < NT; ++t) {
    const int cur = t & 1;
    if (t + 1 < NT) {
      // stage next tile into alternate buffer (4 loads, left in flight)
      char* dA = smem + (cur ^ 1) * 16384 + ldst;
      const char* sa = gA + (size_t)(t + 1) * 64;
      const char* sw = gW + (size_t)(t + 1) * 64;
      gl_lds16(sa, dA);
      gl_lds16(sa + (size_t)64 * KP, dA + 4096);
      gl_lds16(sw, dA + 8192);
      gl_lds16(sw + (size_t)64 * KP, dA + 12288);
      asm volatile("s_waitcnt vmcnt(4)" ::: "memory");  // tile t landed; t+1 in flight
    } else {
      asm volatile("s_waitcnt vmcnt(0)" ::: "memory");  // drain last tile
    }
    __builtin_amdgcn_sched_barrier(0);
    __builtin_amdgcn_s_barrier();  // all waves' stage(t) visible
    __builtin_amdgcn_sched_barrier(0);

    const char* rb = smem + cur * 16384;
    i32x4 af[4], bg[4];
#pragma unroll
    for (int i = 0; i < 4; ++i)
      af[i] = *(const i32x4*)&rb[(wm + 16 * i) * 64 + rdoff];
#pragma unroll
    for (int j = 0; j < 4; ++j)
      bg[j] = *(const i32x4*)&rb[8192 + (wn + 16 * j) * 64 + rdoff];

    asm volatile("s_waitcnt lgkmcnt(0)" ::: "memory");  // reads landed in regs
    __builtin_amdgcn_sched_barrier(0);
    __builtin_amdgcn_s_barrier();  // all waves done reading buf[cur]
    __builtin_amdgcn_sched_barrier(0);

    __builtin_amdgcn_s_setprio(1);
#pragma unroll
    for (int i = 0; i < 4; ++i)
#pragma unroll
      for (int j = 0; j < 4; ++j)
        iacc[i][j] = __builtin_amdgcn_mfma_i32_16x16x64_i8(af[i], bg[j], iacc[i][j], 0, 0, 0);
    __builtin_amdgcn_s_setprio(0);
  }

  // ---- epilogue: preload scales/bias to regs, then reuse smem as C tile ----
  __syncthreads();
  float rs[4][4], cs[4], bvj[4];
#pragma unroll
  for (int i = 0; i < 4; ++i)
#pragma unroll
    for (int r = 0; r < 4; ++r) rs[i][r] = sc0[wm + 16 * i + quad * 4 + r];
#pragma unroll
  for (int j = 0; j < 4; ++j) {
    const int coll = wn + 16 * j + l16;
    cs[j] = sc1[coll];
    bvj[j] = bias[bn + coll];
  }
  unsigned short* ct = (unsigned short*)smem;  // [64][136] u16 = 17408 B
  const int trow = tid >> 4;        // 0..15
  const int tcol = (tid & 15) * 8;  // u16 offset within row
#pragma unroll
  for (int p = 0; p < 2; ++p) {
    __syncthreads();
    if ((wm >> 6) == p) {
#pragma unroll
      for (int i = 0; i < 4; ++i)
#pragma unroll
        for (int j = 0; j < 4; ++j)
#pragma unroll
          for (int r = 0; r < 4; ++r) {
            float v = (float)iacc[i][j][r] * rs[i][r] * cs[j] + bvj[j];
            if (RELU) v = fmaxf(v, 0.f);
            ct[(16 * i + quad * 4 + r) * 136 + wn + 16 * j + l16] = f2bf(v);
          }
    }
    __syncthreads();  // C half-tile staged
#pragma unroll
    for (int s = 0; s < 4; ++s) {
      const int rl = s * 16 + trow;
      i32x4 vv = *(const i32x4*)&ct[rl * 136 + tcol];
      *(i32x4*)&C[(bm + p * 64 + rl) * (long long)N + bn + tcol] = vv;
    }
  }
}

// ---------------- graph boundaries ----------------
__global__ void bounds_k(const int* __restrict__ batch, int* __restrict__ gstart, int n, int G) {
  int g = blockIdx.x * blockDim.x + threadIdx.x;
  if (g > G) return;
  int lo = 0, hi = n;
  while (lo < hi) {
    int mid = (lo + hi) >> 1;
    if (batch[mid] < g) lo = mid + 1; else hi = mid;
  }
  gstart[g] = lo;
}

// ---------------- segment max pool ----------------
__global__ void segmax_k(const unsigned short* __restrict__ h2b, const int* __restrict__ gstart,
                         float* __restrict__ pooled) {
  int g = blockIdx.x;
  int c = blockIdx.y * 256 + threadIdx.x;
  int i0 = gstart[g], i1 = gstart[g + 1];
  float m = -3.4e38f;
  for (int i = i0; i < i1; ++i) m = fmaxf(m, bf2f(h2b[(size_t)i * D2 + c]));
  if (i0 >= i1) m = 0.f;
  pooled[(size_t)g * D2 + c] = m;
}

// ---------------- MLP head (fp32) ----------------
__global__ void head1_k(const float* __restrict__ pooled, const float* __restrict__ Wf1,
                        const float* __restrict__ bf1, float* __restrict__ hid) {
  int g = blockIdx.x, chunk = blockIdx.y;
  __shared__ float sp[2048];
  for (int i = threadIdx.x; i < 2048; i += 256) sp[i] = pooled[(size_t)g * 2048 + i];
  __syncthreads();
  int wave = threadIdx.x >> 6, lane = threadIdx.x & 63;
  for (int oi = wave; oi < 64; oi += 4) {
    int o = chunk * 64 + oi;
    const float4* wr = (const float4*)&Wf1[(size_t)o * 2048];
    float s = 0.f;
    for (int c = lane; c < 512; c += 64) {
      float4 wv = wr[c];
      float4 pv = *(const float4*)&sp[c * 4];
      s += wv.x * pv.x + wv.y * pv.y + wv.z * pv.z + wv.w * pv.w;
    }
    for (int off = 32; off; off >>= 1) s += __shfl_down(s, off);
    if (lane == 0) hid[(size_t)g * 1024 + o] = fmaxf(s + bf1[o], 0.f);
  }
}
__global__ void head2_k(const float* __restrict__ hid, const float* __restrict__ Wf2,
                        const float* __restrict__ bf2, float* __restrict__ out) {
  int g = blockIdx.x, t = threadIdx.x;
  __shared__ float sh[1024];
  __shared__ float red[256];
  for (int i = t; i < 1024; i += 256) sh[i] = hid[(size_t)g * 1024 + i];
  __syncthreads();
  for (int o = 0; o < 6; ++o) {
    float s = 0.f;
    for (int k = t; k < 1024; k += 256) s += sh[k] * Wf2[o * 1024 + k];
    red[t] = s;
    __syncthreads();
    for (int d = 128; d; d >>= 1) {
      if (t < d) red[t] += red[t + d];
      __syncthreads();
    }
    if (t == 0) out[g * 6 + o] = red[0] + bf2[o];
    __syncthreads();
  }
}

extern "C" void kernel_launch(void* const* d_in, const int* in_sizes, int n_in,
                              void* d_out, int out_size, void* d_ws, size_t ws_size,
                              hipStream_t stream) {
  const float* x    = (const float*)d_in[0];
  const int* ei     = (const int*)d_in[1];
  const int* batch  = (const int*)d_in[2];
  const float* W1l  = (const float*)d_in[3];
  const float* b1   = (const float*)d_in[4];
  const float* W1r  = (const float*)d_in[5];
  const float* W2l  = (const float*)d_in[6];
  const float* b2   = (const float*)d_in[7];
  const float* W2r  = (const float*)d_in[8];
  const float* Wf1  = (const float*)d_in[9];
  const float* bf1  = (const float*)d_in[10];
  const float* Wf2  = (const float*)d_in[11];
  const float* bf2  = (const float*)d_in[12];
  float* out = (float*)d_out;

  const int E = in_sizes[1] / 2;
  const int* srcp = ei;
  const int* dstp = ei + E;
  const int NB = (MP + 255) / 256;  // scan blocks

  char* w = (char*)d_ws;
  auto take = [&](size_t b) {
    void* p = (void*)w;
    w += (b + 255) & ~(size_t)255;
    return p;
  };
  char* cat1      = (char*)take((size_t)MP * KC1);        // [mean | x] int8
  char* cat2      = (char*)take((size_t)MP * KC2);        // [mean2 | h1] int8
  unsigned short* h1b = (unsigned short*)take((size_t)MP * D1 * 2);
  unsigned short* h2b = (unsigned short*)take((size_t)MP * D2 * 2);
  char* wcat1     = (char*)take((size_t)D1 * KC1);
  char* wcat2     = (char*)take((size_t)D2 * KC2);
  float* xscale   = (float*)take((size_t)MP * 4);
  float* h1scale  = (float*)take((size_t)MP * 4);
  float* swc1     = (float*)take((size_t)D1 * 4);
  float* swc2     = (float*)take((size_t)D2 * 4);
  int* deg    = (int*)take((size_t)MP * 4);
  int* off    = (int*)take((size_t)(MP + 1) * 4);
  int* bsum   = (int*)take((size_t)(NB + 1) * 4);
  int* cursor = (int*)take((size_t)MP * 4);
  int* csr    = (int*)take((size_t)E * 4);
  int* gstart = (int*)take((size_t)(NG + 1) * 4);
  float* pooled = (float*)take((size_t)NG * D2 * 4);
  float* hid    = (float*)take((size_t)NG * 1024 * 4);

  cvt_x<<<MP, 256, 0, stream>>>(x, cat1, xscale);
  wq_cat<<<D1, 256, 0, stream>>>(W1l, W1r, D0, K0, wcat1, swc1);
  wq_cat<<<D2, 256, 0, stream>>>(W2l, W2r, D1, D1, wcat2, swc2);

  zero_i<<<(MP + 255) / 256, 256, 0, stream>>>(deg, MP);
  count_k<<<(E + 255) / 256, 256, 0, stream>>>(dstp, deg, E, NN);
  scan1_k<<<NB, 256, 0, stream>>>(deg, off, bsum, MP);
  scan2_k<<<1, 256, 0, stream>>>(bsum, NB);
  scan3_k<<<NB, 256, 0, stream>>>(off, bsum, MP, NB);
  copy_i<<<(MP + 255) / 256, 256, 0, stream>>>(off, cursor, MP);
  fill_k<<<(E + 255) / 256, 256, 0, stream>>>(srcp, dstp, cursor, csr, E, NN);

  // conv1: mean half of cat1 <- agg(x half); h1 = relu(cat1 @ wcat1^T + b1)
  agg_mean_i8w<K0, KC1><<<MP / 4, 256, 0, stream>>>(cat1, xscale, off, csr);
  gemm_i8<KC1, D1, true><<<dim3(D1 / 128, MP / 128), 256, 0, stream>>>(
      cat1, wcat1, xscale, swc1, b1, h1b);

  // conv2: quantize h1 into cat2; mean2 half <- agg(h1 half); h2 = cat2 @ wcat2^T + b2
  quant_rows<<<MP, 256, 0, stream>>>(h1b, cat2, h1scale);
  agg_mean_i8w<D1, KC2><<<MP / 4, 256, 0, stream>>>(cat2, h1scale, off, csr);
  gemm_i8<KC2, D2, false><<<dim3(D2 / 128, MP / 128), 256, 0, stream>>>(
      cat2, wcat2, h1scale, swc2, b2, h2b);

  bounds_k<<<1, 128, 0, stream>>>(batch, gstart, NN, NG);
  segmax_k<<<dim3(NG, D2 / 256), 256, 0, stream>>>(h2b, gstart, pooled);
  head1_k<<<dim3(NG, 16), 256, 0, stream>>>(pooled, Wf1, bf1, hid);
  head2_k<<<NG, 256, 0, stream>>>(hid, Wf2, bf2, out);
}

// Round 4
// 1634.487 us; speedup vs baseline: 1.1211x; 1.0195x over previous
//
#include <hip/hip_runtime.h>

typedef unsigned short u16x8 __attribute__((ext_vector_type(8)));
typedef char i8x16 __attribute__((ext_vector_type(16)));
typedef int i32x4 __attribute__((ext_vector_type(4)));

constexpr int NN = 50000;   // nodes
constexpr int NG = 64;      // graphs
constexpr int MP = 50176;   // nodes padded to 256 (196*256)
constexpr int D0 = 900;     // input feature dim
constexpr int K0 = 960;     // conv1 half-K padded to 64
constexpr int D1 = 1024;    // conv1 out dim / conv2 half-K
constexpr int D2 = 2048;    // conv2 out dim
constexpr int KC1 = 2 * K0; // conv1 concatenated K = 1920
constexpr int KC2 = 2 * D1; // conv2 concatenated K = 2048

__device__ __forceinline__ float bf2f(unsigned short u) {
  return __uint_as_float(((unsigned)u) << 16);
}
__device__ __forceinline__ unsigned short f2bf(float f) {
  unsigned x = __float_as_uint(f);
  return (unsigned short)((x + 0x7fffu + ((x >> 16) & 1u)) >> 16);
}

__device__ __forceinline__ void gl_lds16(const void* g, void* l) {
  __builtin_amdgcn_global_load_lds((const __attribute__((address_space(1))) void*)g,
                                   (__attribute__((address_space(3))) void*)l, 16, 0, 0);
}

// ------- x: fp32 -> int8 into x-half of cat1, per-row scale -------
__global__ __launch_bounds__(256) void cvt_x(const float* __restrict__ in,
                                             char* __restrict__ cat1,
                                             float* __restrict__ xscale) {
  int r = blockIdx.x;
  __shared__ float row[K0];
  __shared__ float smax[256];
  int t = threadIdx.x;
  float m = 0.f;
  for (int c = t; c < K0; c += 256) {
    float v = (r < NN && c < D0) ? in[(size_t)r * D0 + c] : 0.f;
    row[c] = v;
    m = fmaxf(m, fabsf(v));
  }
  smax[t] = m;
  __syncthreads();
  for (int dd = 128; dd; dd >>= 1) {
    if (t < dd) smax[t] = fmaxf(smax[t], smax[t + dd]);
    __syncthreads();
  }
  float mx = smax[0];
  float inv = mx > 0.f ? 127.f / mx : 0.f;
  char* dst = cat1 + (size_t)r * KC1 + K0;  // x goes in second half
  for (int c = t; c < K0; c += 256) dst[c] = (char)(int)rintf(row[c] * inv);
  if (t == 0) xscale[r] = mx * (1.f / 127.f);
}

// ------- weights: [Wl | Wr] -> int8 cat with shared per-out-row scale -------
__global__ __launch_bounds__(256) void wq_cat(const float* __restrict__ Wl,
                                              const float* __restrict__ Wr, int Cin, int KH,
                                              char* __restrict__ q, float* __restrict__ sc) {
  int r = blockIdx.x, t = threadIdx.x;
  __shared__ float smax[256];
  float m = 0.f;
  for (int c = t; c < Cin; c += 256) {
    m = fmaxf(m, fabsf(Wl[(size_t)r * Cin + c]));
    m = fmaxf(m, fabsf(Wr[(size_t)r * Cin + c]));
  }
  smax[t] = m;
  __syncthreads();
  for (int dd = 128; dd; dd >>= 1) {
    if (t < dd) smax[t] = fmaxf(smax[t], smax[t + dd]);
    __syncthreads();
  }
  float mx = smax[0];
  float inv = mx > 0.f ? 127.f / mx : 0.f;
  char* row = q + (size_t)r * 2 * KH;
  for (int c = t; c < KH; c += 256) {
    row[c]      = (c < Cin) ? (char)(int)rintf(Wl[(size_t)r * Cin + c] * inv) : 0;
    row[KH + c] = (c < Cin) ? (char)(int)rintf(Wr[(size_t)r * Cin + c] * inv) : 0;
  }
  if (t == 0) sc[r] = mx * (1.f / 127.f);
}

// ------- h1 bf16 rows -> int8 into h1-half of cat2, per-row scale -------
__global__ __launch_bounds__(256) void quant_rows(const unsigned short* __restrict__ in,
                                                  char* __restrict__ cat2,
                                                  float* __restrict__ scale) {
  int r = blockIdx.x;
  __shared__ float row[D1];
  __shared__ float smax[256];
  int t = threadIdx.x;
  float m = 0.f;
  for (int c = t; c < D1; c += 256) {
    float v = bf2f(in[(size_t)r * D1 + c]);
    row[c] = v;
    m = fmaxf(m, fabsf(v));
  }
  smax[t] = m;
  __syncthreads();
  for (int dd = 128; dd; dd >>= 1) {
    if (t < dd) smax[t] = fmaxf(smax[t], smax[t + dd]);
    __syncthreads();
  }
  float mx = smax[0];
  float inv = mx > 0.f ? 127.f / mx : 0.f;
  char* dst = cat2 + (size_t)r * KC2 + D1;  // h1 goes in second half
  for (int c = t; c < D1; c += 256) dst[c] = (char)(int)rintf(row[c] * inv);
  if (t == 0) scale[r] = mx * (1.f / 127.f);
}

// ---------------- CSR build ----------------
__global__ void zero_i(int* p, int n) {
  int i = blockIdx.x * blockDim.x + threadIdx.x;
  if (i < n) p[i] = 0;
}
__global__ void count_k(const int* __restrict__ dst, int* __restrict__ deg, int E, int n) {
  int e = blockIdx.x * blockDim.x + threadIdx.x;
  if (e < E) {
    int d = dst[e];
    if ((unsigned)d < (unsigned)n) atomicAdd(&deg[d], 1);
  }
}
// hierarchical scan: block-local -> block sums -> add offsets
__global__ void scan1_k(const int* __restrict__ deg, int* __restrict__ off,
                        int* __restrict__ bsum, int n) {
  __shared__ int s[256];
  int t = threadIdx.x;
  int gid = blockIdx.x * 256 + t;
  int v = (gid < n) ? deg[gid] : 0;
  s[t] = v;
  __syncthreads();
  for (int d = 1; d < 256; d <<= 1) {
    int x = (t >= d) ? s[t - d] : 0;
    __syncthreads();
    s[t] += x;
    __syncthreads();
  }
  if (gid < n) off[gid] = s[t] - v;
  if (t == 255) bsum[blockIdx.x] = s[255];
}
__global__ void scan2_k(int* __restrict__ bsum, int nb) {
  __shared__ int s[256];
  int t = threadIdx.x;
  int v = (t < nb) ? bsum[t] : 0;
  s[t] = v;
  __syncthreads();
  for (int d = 1; d < 256; d <<= 1) {
    int x = (t >= d) ? s[t - d] : 0;
    __syncthreads();
    s[t] += x;
    __syncthreads();
  }
  if (t < nb) bsum[t] = s[t] - v;
  if (t == 255) bsum[nb] = s[255];
}
__global__ void scan3_k(int* __restrict__ off, const int* __restrict__ bsum, int n, int nb) {
  int gid = blockIdx.x * 256 + threadIdx.x;
  if (gid < n) off[gid] += bsum[gid >> 8];
  if (gid == 0) off[n] = bsum[nb];
}
__global__ void copy_i(const int* a, int* b, int n) {
  int i = blockIdx.x * blockDim.x + threadIdx.x;
  if (i < n) b[i] = a[i];
}
__global__ void fill_k(const int* __restrict__ src, const int* __restrict__ dst,
                       int* __restrict__ cursor, int* __restrict__ csr, int E, int n) {
  int e = blockIdx.x * blockDim.x + threadIdx.x;
  if (e < E) {
    int d = dst[e];
    if ((unsigned)d < (unsigned)n) {
      int p = atomicAdd(&cursor[d], 1);
      int s = src[e];
      if ((unsigned)s >= (unsigned)n) s = 0;
      csr[p] = s;
    }
  }
}

// ------- mean aggregation: one wave per node, int8 gather, int8 out -------
template <int K, int STRIDE>
__global__ __launch_bounds__(256) void agg_mean_i8w(char* __restrict__ cat,
                                                    const float* __restrict__ rscale,
                                                    const int* __restrict__ off,
                                                    const int* __restrict__ csr) {
  const int node = blockIdx.x * 4 + (threadIdx.x >> 6);
  const int lane = threadIdx.x & 63;
  const int d = lane * 16;
  const bool act = (d < K);
  const int e0 = off[node], e1 = off[node + 1];
  float a[16];
#pragma unroll
  for (int k = 0; k < 16; ++k) a[k] = 0.f;
  if (act) {
    const char* fp = cat + (size_t)K + d;  // feature half base + lane offset
    int e = e0;
    for (; e + 7 < e1; e += 8) {
      int s0 = csr[e],     s1 = csr[e + 1], s2 = csr[e + 2], s3 = csr[e + 3];
      int s4 = csr[e + 4], s5 = csr[e + 5], s6 = csr[e + 6], s7 = csr[e + 7];
      i8x16 v0 = *(const i8x16*)(fp + (size_t)s0 * STRIDE);
      i8x16 v1 = *(const i8x16*)(fp + (size_t)s1 * STRIDE);
      i8x16 v2 = *(const i8x16*)(fp + (size_t)s2 * STRIDE);
      i8x16 v3 = *(const i8x16*)(fp + (size_t)s3 * STRIDE);
      i8x16 v4 = *(const i8x16*)(fp + (size_t)s4 * STRIDE);
      i8x16 v5 = *(const i8x16*)(fp + (size_t)s5 * STRIDE);
      i8x16 v6 = *(const i8x16*)(fp + (size_t)s6 * STRIDE);
      i8x16 v7 = *(const i8x16*)(fp + (size_t)s7 * STRIDE);
      float c0 = rscale[s0], c1 = rscale[s1], c2 = rscale[s2], c3 = rscale[s3];
      float c4 = rscale[s4], c5 = rscale[s5], c6 = rscale[s6], c7 = rscale[s7];
#pragma unroll
      for (int k = 0; k < 16; ++k) {
        a[k] += c0 * (float)v0[k] + c1 * (float)v1[k] + c2 * (float)v2[k] + c3 * (float)v3[k];
        a[k] += c4 * (float)v4[k] + c5 * (float)v5[k] + c6 * (float)v6[k] + c7 * (float)v7[k];
      }
    }
    for (; e < e1; ++e) {
      int s = csr[e];
      float c = rscale[s];
      i8x16 v = *(const i8x16*)(fp + (size_t)s * STRIDE);
#pragma unroll
      for (int k = 0; k < 16; ++k) a[k] += c * (float)v[k];
    }
  }
  if (act) {
    int deg = e1 - e0;
    float inv = 1.f / (float)(deg > 1 ? deg : 1);
    float sc = rscale[node];
    float qi = sc > 0.f ? 1.f / sc : 0.f;  // quantize mean with row's own scale
    i8x16 q;
#pragma unroll
    for (int k = 0; k < 16; ++k) {
      float m = a[k] * inv * qi;
      m = fminf(fmaxf(rintf(m), -127.f), 127.f);
      q[k] = (char)(int)m;
    }
    *(i8x16*)&cat[(size_t)node * STRIDE + d] = q;  // mean half
  }
}

// ---------------- single-pass K-concatenated int8 MFMA GEMM ----------------
// C[m,n] = relu?( sA(m)*sW(n)*sum_k A[m,k]W[n,k] + bias[n] ), bf16 out.
// 256x128 tile (170 int8-ops/byte vs L2 parity at 128), 8 waves (4M x 2N),
// each wave a 64x64 sub-tile of mfma_i32_16x16x64_i8.
// T1: bijective XCD block swizzle (A-panel reuse within one L2).
// T3+T4: double-buffered LDS + counted s_waitcnt vmcnt(3) across raw s_barrier.
// T2: conflict-free LDS read swizzle via pre-swizzled GLOBAL source chunk
//     (LDS dest stays linear for global_load_lds): content[row][s] = chunk
//     s ^ ((row>>1)&3); read slot = quad ^ ((l16>>1)&3).
// T5: s_setprio(1) around the MFMA cluster.
// Epilogue stages C through LDS and stores full 256B row segments (no RMW).
template <int KP, int N, bool RELU>
__global__ __launch_bounds__(512, 4) void gemm_i8(const char* __restrict__ A,
                                                  const char* __restrict__ W,
                                                  const float* __restrict__ sA_,
                                                  const float* __restrict__ sW_,
                                                  const float* __restrict__ bias,
                                                  unsigned short* __restrict__ C) {
  // double buffer: [2][ A:16384 | B:8192 ] + scales (sc0:256, sc1:128)
  __shared__ __align__(16) char smem[50688];
  float* sc0 = (float*)(smem + 49152);
  float* sc1 = sc0 + 256;

  // bijective XCD swizzle: each XCD gets a contiguous chunk of work ids,
  // x (N-dim) fastest inside the chunk -> A-panel reuse within one L2.
  const int gx = gridDim.x;
  const int nwg = gx * gridDim.y;
  const int flat = blockIdx.y * gx + blockIdx.x;
  int newid = flat;
  if ((nwg & 7) == 0) newid = (flat & 7) * (nwg >> 3) + (flat >> 3);
  const int bxi = newid % gx;
  const int byi = newid / gx;

  const int tid = threadIdx.x;
  const int wave = tid >> 6, lane = tid & 63;
  const int quad = lane >> 4, l16 = lane & 15;
  const int wm = (wave >> 1) * 64, wn = (wave & 1) * 64;  // wm {0,64,128,192}, wn {0,64}
  const long long bm = (long long)byi * 256;
  const long long bn = (long long)bxi * 128;

  if (tid < 256) sc0[tid] = sA_[bm + tid];
  else if (tid < 384) sc1[tid - 256] = sW_[bn + tid - 256];

  // staging: thread t covers row t>>2 (A also +128), swizzled chunk
  const int srow = tid >> 2;                       // 0..127
  const int cswz = (tid & 3) ^ ((tid >> 3) & 3);   // = slot ^ ((row>>1)&3)
  const int ldst = tid * 16;
  const char* gA = A + (bm + srow) * (long long)KP + cswz * 16;
  const char* gW = W + (bn + srow) * (long long)KP + cswz * 16;

  // fragment-read sub-offset: slot = quad ^ ((l16>>1)&3)
  const int rdoff = (quad ^ ((l16 >> 1) & 3)) << 4;

  i32x4 iacc[4][4];
#pragma unroll
  for (int i = 0; i < 4; ++i)
#pragma unroll
    for (int j = 0; j < 4; ++j) iacc[i][j] = (i32x4){0, 0, 0, 0};

  constexpr int NT = KP / 64;

  // prologue: stage tile 0 into buffer 0 (A-lo, A-hi, B = 3 loads/wave)
  {
    char* d = smem + ldst;
    gl_lds16(gA, d);
    gl_lds16(gA + (size_t)128 * KP, d + 8192);
    gl_lds16(gW, d + 16384);
  }

#pragma unroll 1
  for (int t = 0; t < NT; ++t) {
    const int cur = t & 1;
    if (t + 1 < NT) {
      // stage next tile into alternate buffer (3 loads, left in flight)
      char* d = smem + (cur ^ 1) * 24576 + ldst;
      const char* sa = gA + (size_t)(t + 1) * 64;
      const char* sw = gW + (size_t)(t + 1) * 64;
      gl_lds16(sa, d);
      gl_lds16(sa + (size_t)128 * KP, d + 8192);
      gl_lds16(sw, d + 16384);
      asm volatile("s_waitcnt vmcnt(3)" ::: "memory");  // tile t landed; t+1 in flight
    } else {
      asm volatile("s_waitcnt vmcnt(0)" ::: "memory");  // drain last tile
    }
    __builtin_amdgcn_sched_barrier(0);
    __builtin_amdgcn_s_barrier();  // all waves' stage(t) visible
    __builtin_amdgcn_sched_barrier(0);

    const char* rb = smem + cur * 24576;
    i32x4 af[4], bg[4];
#pragma unroll
    for (int i = 0; i < 4; ++i)
      af[i] = *(const i32x4*)&rb[(wm + 16 * i + l16) * 64 + rdoff];
#pragma unroll
    for (int j = 0; j < 4; ++j)
      bg[j] = *(const i32x4*)&rb[16384 + (wn + 16 * j + l16) * 64 + rdoff];

    asm volatile("s_waitcnt lgkmcnt(0)" ::: "memory");  // reads landed in regs
    __builtin_amdgcn_sched_barrier(0);
    __builtin_amdgcn_s_barrier();  // all waves done reading buf[cur]
    __builtin_amdgcn_sched_barrier(0);

    __builtin_amdgcn_s_setprio(1);
#pragma unroll
    for (int i = 0; i < 4; ++i)
#pragma unroll
      for (int j = 0; j < 4; ++j)
        iacc[i][j] = __builtin_amdgcn_mfma_i32_16x16x64_i8(af[i], bg[j], iacc[i][j], 0, 0, 0);
    __builtin_amdgcn_s_setprio(0);
  }

  // ---- epilogue: scales/bias to regs, reuse smem[0..34816) as C tile ----
  __syncthreads();
  float rs[4][4], cs[4], bvj[4];
#pragma unroll
  for (int i = 0; i < 4; ++i)
#pragma unroll
    for (int r = 0; r < 4; ++r) rs[i][r] = sc0[wm + 16 * i + quad * 4 + r];
#pragma unroll
  for (int j = 0; j < 4; ++j) {
    const int coll = wn + 16 * j + l16;
    cs[j] = sc1[coll];
    bvj[j] = bias[bn + coll];
  }
  unsigned short* ct = (unsigned short*)smem;  // [128][136] u16 = 34816 B
  const int trow = tid >> 4;        // 0..31
  const int tcol = (tid & 15) * 8;  // u16 offset within row
#pragma unroll
  for (int p = 0; p < 2; ++p) {
    __syncthreads();
    if ((wm >> 7) == p) {
      const int lbase = wm - p * 128;
#pragma unroll
      for (int i = 0; i < 4; ++i)
#pragma unroll
        for (int j = 0; j < 4; ++j)
#pragma unroll
          for (int r = 0; r < 4; ++r) {
            float v = (float)iacc[i][j][r] * rs[i][r] * cs[j] + bvj[j];
            if (RELU) v = fmaxf(v, 0.f);
            ct[(lbase + 16 * i + quad * 4 + r) * 136 + wn + 16 * j + l16] = f2bf(v);
          }
    }
    __syncthreads();  // C half-tile staged
#pragma unroll
    for (int s = 0; s < 4; ++s) {
      const int rl = s * 32 + trow;
      i32x4 vv = *(const i32x4*)&ct[rl * 136 + tcol];
      *(i32x4*)&C[(bm + p * 128 + rl) * (long long)N + bn + tcol] = vv;
    }
  }
}

// ---------------- graph boundaries ----------------
__global__ void bounds_k(const int* __restrict__ batch, int* __restrict__ gstart, int n, int G) {
  int g = blockIdx.x * blockDim.x + threadIdx.x;
  if (g > G) return;
  int lo = 0, hi = n;
  while (lo < hi) {
    int mid = (lo + hi) >> 1;
    if (batch[mid] < g) lo = mid + 1; else hi = mid;
  }
  gstart[g] = lo;
}

// ---------------- segment max pool ----------------
__global__ void segmax_k(const unsigned short* __restrict__ h2b, const int* __restrict__ gstart,
                         float* __restrict__ pooled) {
  int g = blockIdx.x;
  int c = blockIdx.y * 256 + threadIdx.x;
  int i0 = gstart[g], i1 = gstart[g + 1];
  float m = -3.4e38f;
  for (int i = i0; i < i1; ++i) m = fmaxf(m, bf2f(h2b[(size_t)i * D2 + c]));
  if (i0 >= i1) m = 0.f;
  pooled[(size_t)g * D2 + c] = m;
}

// ---------------- MLP head (fp32) ----------------
__global__ void head1_k(const float* __restrict__ pooled, const float* __restrict__ Wf1,
                        const float* __restrict__ bf1, float* __restrict__ hid) {
  int g = blockIdx.x, chunk = blockIdx.y;
  __shared__ float sp[2048];
  for (int i = threadIdx.x; i < 2048; i += 256) sp[i] = pooled[(size_t)g * 2048 + i];
  __syncthreads();
  int wave = threadIdx.x >> 6, lane = threadIdx.x & 63;
  for (int oi = wave; oi < 64; oi += 4) {
    int o = chunk * 64 + oi;
    const float4* wr = (const float4*)&Wf1[(size_t)o * 2048];
    float s = 0.f;
    for (int c = lane; c < 512; c += 64) {
      float4 wv = wr[c];
      float4 pv = *(const float4*)&sp[c * 4];
      s += wv.x * pv.x + wv.y * pv.y + wv.z * pv.z + wv.w * pv.w;
    }
    for (int off = 32; off; off >>= 1) s += __shfl_down(s, off);
    if (lane == 0) hid[(size_t)g * 1024 + o] = fmaxf(s + bf1[o], 0.f);
  }
}
__global__ void head2_k(const float* __restrict__ hid, const float* __restrict__ Wf2,
                        const float* __restrict__ bf2, float* __restrict__ out) {
  int g = blockIdx.x, t = threadIdx.x;
  __shared__ float sh[1024];
  __shared__ float red[256];
  for (int i = t; i < 1024; i += 256) sh[i] = hid[(size_t)g * 1024 + i];
  __syncthreads();
  for (int o = 0; o < 6; ++o) {
    float s = 0.f;
    for (int k = t; k < 1024; k += 256) s += sh[k] * Wf2[o * 1024 + k];
    red[t] = s;
    __syncthreads();
    for (int d = 128; d; d >>= 1) {
      if (t < d) red[t] += red[t + d];
      __syncthreads();
    }
    if (t == 0) out[g * 6 + o] = red[0] + bf2[o];
    __syncthreads();
  }
}

extern "C" void kernel_launch(void* const* d_in, const int* in_sizes, int n_in,
                              void* d_out, int out_size, void* d_ws, size_t ws_size,
                              hipStream_t stream) {
  const float* x    = (const float*)d_in[0];
  const int* ei     = (const int*)d_in[1];
  const int* batch  = (const int*)d_in[2];
  const float* W1l  = (const float*)d_in[3];
  const float* b1   = (const float*)d_in[4];
  const float* W1r  = (const float*)d_in[5];
  const float* W2l  = (const float*)d_in[6];
  const float* b2   = (const float*)d_in[7];
  const float* W2r  = (const float*)d_in[8];
  const float* Wf1  = (const float*)d_in[9];
  const float* bf1  = (const float*)d_in[10];
  const float* Wf2  = (const float*)d_in[11];
  const float* bf2  = (const float*)d_in[12];
  float* out = (float*)d_out;

  const int E = in_sizes[1] / 2;
  const int* srcp = ei;
  const int* dstp = ei + E;
  const int NB = (MP + 255) / 256;  // scan blocks

  char* w = (char*)d_ws;
  auto take = [&](size_t b) {
    void* p = (void*)w;
    w += (b + 255) & ~(size_t)255;
    return p;
  };
  char* cat1      = (char*)take((size_t)MP * KC1);        // [mean | x] int8
  char* cat2      = (char*)take((size_t)MP * KC2);        // [mean2 | h1] int8
  unsigned short* h1b = (unsigned short*)take((size_t)MP * D1 * 2);
  unsigned short* h2b = (unsigned short*)take((size_t)MP * D2 * 2);
  char* wcat1     = (char*)take((size_t)D1 * KC1);
  char* wcat2     = (char*)take((size_t)D2 * KC2);
  float* xscale   = (float*)take((size_t)MP * 4);
  float* h1scale  = (float*)take((size_t)MP * 4);
  float* swc1     = (float*)take((size_t)D1 * 4);
  float* swc2     = (float*)take((size_t)D2 * 4);
  int* deg    = (int*)take((size_t)MP * 4);
  int* off    = (int*)take((size_t)(MP + 1) * 4);
  int* bsum   = (int*)take((size_t)(NB + 1) * 4);
  int* cursor = (int*)take((size_t)MP * 4);
  int* csr    = (int*)take((size_t)E * 4);
  int* gstart = (int*)take((size_t)(NG + 1) * 4);
  float* pooled = (float*)take((size_t)NG * D2 * 4);
  float* hid    = (float*)take((size_t)NG * 1024 * 4);

  cvt_x<<<MP, 256, 0, stream>>>(x, cat1, xscale);
  wq_cat<<<D1, 256, 0, stream>>>(W1l, W1r, D0, K0, wcat1, swc1);
  wq_cat<<<D2, 256, 0, stream>>>(W2l, W2r, D1, D1, wcat2, swc2);

  zero_i<<<(MP + 255) / 256, 256, 0, stream>>>(deg, MP);
  count_k<<<(E + 255) / 256, 256, 0, stream>>>(dstp, deg, E, NN);
  scan1_k<<<NB, 256, 0, stream>>>(deg, off, bsum, MP);
  scan2_k<<<1, 256, 0, stream>>>(bsum, NB);
  scan3_k<<<NB, 256, 0, stream>>>(off, bsum, MP, NB);
  copy_i<<<(MP + 255) / 256, 256, 0, stream>>>(off, cursor, MP);
  fill_k<<<(E + 255) / 256, 256, 0, stream>>>(srcp, dstp, cursor, csr, E, NN);

  // conv1: mean half of cat1 <- agg(x half); h1 = relu(cat1 @ wcat1^T + b1)
  agg_mean_i8w<K0, KC1><<<MP / 4, 256, 0, stream>>>(cat1, xscale, off, csr);
  gemm_i8<KC1, D1, true><<<dim3(D1 / 128, MP / 256), 512, 0, stream>>>(
      cat1, wcat1, xscale, swc1, b1, h1b);

  // conv2: quantize h1 into cat2; mean2 half <- agg(h1 half); h2 = cat2 @ wcat2^T + b2
  quant_rows<<<MP, 256, 0, stream>>>(h1b, cat2, h1scale);
  agg_mean_i8w<D1, KC2><<<MP / 4, 256, 0, stream>>>(cat2, h1scale, off, csr);
  gemm_i8<KC2, D2, false><<<dim3(D2 / 128, MP / 256), 512, 0, stream>>>(
      cat2, wcat2, h1scale, swc2, b2, h2b);

  bounds_k<<<1, 128, 0, stream>>>(batch, gstart, NN, NG);
  segmax_k<<<dim3(NG, D2 / 256), 256, 0, stream>>>(h2b, gstart, pooled);
  head1_k<<<dim3(NG, 16), 256, 0, stream>>>(pooled, Wf1, bf1, hid);
  head2_k<<<NG, 256, 0, stream>>>(hid, Wf2, bf2, out);
}

// Round 5
// 1631.113 us; speedup vs baseline: 1.1234x; 1.0021x over previous
//
#include <hip/hip_runtime.h>

typedef unsigned short u16x8 __attribute__((ext_vector_type(8)));
typedef char i8x16 __attribute__((ext_vector_type(16)));
typedef int i32x4 __attribute__((ext_vector_type(4)));

constexpr int NN = 50000;   // nodes
constexpr int NG = 64;      // graphs
constexpr int MP = 50176;   // nodes padded to 256 (196*256)
constexpr int D0 = 900;     // input feature dim
constexpr int K0 = 960;     // conv1 half-K padded to 64
constexpr int D1 = 1024;    // conv1 out dim / conv2 half-K
constexpr int D2 = 2048;    // conv2 out dim
constexpr int KC1 = 2 * K0; // conv1 concatenated K = 1920
constexpr int KC2 = 2 * D1; // conv2 concatenated K = 2048

__device__ __forceinline__ float bf2f(unsigned short u) {
  return __uint_as_float(((unsigned)u) << 16);
}
__device__ __forceinline__ unsigned short f2bf(float f) {
  unsigned x = __float_as_uint(f);
  return (unsigned short)((x + 0x7fffu + ((x >> 16) & 1u)) >> 16);
}

__device__ __forceinline__ void gl_lds16(const void* g, void* l) {
  __builtin_amdgcn_global_load_lds((const __attribute__((address_space(1))) void*)g,
                                   (__attribute__((address_space(3))) void*)l, 16, 0, 0);
}

// ------- x: fp32 -> int8 into x-half of cat1, per-row scale -------
__global__ __launch_bounds__(256) void cvt_x(const float* __restrict__ in,
                                             char* __restrict__ cat1,
                                             float* __restrict__ xscale) {
  int r = blockIdx.x;
  __shared__ float row[K0];
  __shared__ float smax[256];
  int t = threadIdx.x;
  float m = 0.f;
  for (int c = t; c < K0; c += 256) {
    float v = (r < NN && c < D0) ? in[(size_t)r * D0 + c] : 0.f;
    row[c] = v;
    m = fmaxf(m, fabsf(v));
  }
  smax[t] = m;
  __syncthreads();
  for (int dd = 128; dd; dd >>= 1) {
    if (t < dd) smax[t] = fmaxf(smax[t], smax[t + dd]);
    __syncthreads();
  }
  float mx = smax[0];
  float inv = mx > 0.f ? 127.f / mx : 0.f;
  char* dst = cat1 + (size_t)r * KC1 + K0;  // x goes in second half
  for (int c = t; c < K0; c += 256) dst[c] = (char)(int)rintf(row[c] * inv);
  if (t == 0) xscale[r] = mx * (1.f / 127.f);
}

// ------- weights: [Wl | Wr] -> int8 cat with shared per-out-row scale -------
__global__ __launch_bounds__(256) void wq_cat(const float* __restrict__ Wl,
                                              const float* __restrict__ Wr, int Cin, int KH,
                                              char* __restrict__ q, float* __restrict__ sc) {
  int r = blockIdx.x, t = threadIdx.x;
  __shared__ float smax[256];
  float m = 0.f;
  for (int c = t; c < Cin; c += 256) {
    m = fmaxf(m, fabsf(Wl[(size_t)r * Cin + c]));
    m = fmaxf(m, fabsf(Wr[(size_t)r * Cin + c]));
  }
  smax[t] = m;
  __syncthreads();
  for (int dd = 128; dd; dd >>= 1) {
    if (t < dd) smax[t] = fmaxf(smax[t], smax[t + dd]);
    __syncthreads();
  }
  float mx = smax[0];
  float inv = mx > 0.f ? 127.f / mx : 0.f;
  char* row = q + (size_t)r * 2 * KH;
  for (int c = t; c < KH; c += 256) {
    row[c]      = (c < Cin) ? (char)(int)rintf(Wl[(size_t)r * Cin + c] * inv) : 0;
    row[KH + c] = (c < Cin) ? (char)(int)rintf(Wr[(size_t)r * Cin + c] * inv) : 0;
  }
  if (t == 0) sc[r] = mx * (1.f / 127.f);
}

// ------- h1 bf16 rows -> int8 into h1-half of cat2, per-row scale -------
__global__ __launch_bounds__(256) void quant_rows(const unsigned short* __restrict__ in,
                                                  char* __restrict__ cat2,
                                                  float* __restrict__ scale) {
  int r = blockIdx.x;
  __shared__ float row[D1];
  __shared__ float smax[256];
  int t = threadIdx.x;
  float m = 0.f;
  for (int c = t; c < D1; c += 256) {
    float v = bf2f(in[(size_t)r * D1 + c]);
    row[c] = v;
    m = fmaxf(m, fabsf(v));
  }
  smax[t] = m;
  __syncthreads();
  for (int dd = 128; dd; dd >>= 1) {
    if (t < dd) smax[t] = fmaxf(smax[t], smax[t + dd]);
    __syncthreads();
  }
  float mx = smax[0];
  float inv = mx > 0.f ? 127.f / mx : 0.f;
  char* dst = cat2 + (size_t)r * KC2 + D1;  // h1 goes in second half
  for (int c = t; c < D1; c += 256) dst[c] = (char)(int)rintf(row[c] * inv);
  if (t == 0) scale[r] = mx * (1.f / 127.f);
}

// ---------------- CSR build ----------------
__global__ void zero_i(int* p, int n) {
  int i = blockIdx.x * blockDim.x + threadIdx.x;
  if (i < n) p[i] = 0;
}
__global__ void count_k(const int* __restrict__ dst, int* __restrict__ deg, int E, int n) {
  int e = blockIdx.x * blockDim.x + threadIdx.x;
  if (e < E) {
    int d = dst[e];
    if ((unsigned)d < (unsigned)n) atomicAdd(&deg[d], 1);
  }
}
// hierarchical scan: block-local -> block sums -> add offsets
__global__ void scan1_k(const int* __restrict__ deg, int* __restrict__ off,
                        int* __restrict__ bsum, int n) {
  __shared__ int s[256];
  int t = threadIdx.x;
  int gid = blockIdx.x * 256 + t;
  int v = (gid < n) ? deg[gid] : 0;
  s[t] = v;
  __syncthreads();
  for (int d = 1; d < 256; d <<= 1) {
    int x = (t >= d) ? s[t - d] : 0;
    __syncthreads();
    s[t] += x;
    __syncthreads();
  }
  if (gid < n) off[gid] = s[t] - v;
  if (t == 255) bsum[blockIdx.x] = s[255];
}
__global__ void scan2_k(int* __restrict__ bsum, int nb) {
  __shared__ int s[256];
  int t = threadIdx.x;
  int v = (t < nb) ? bsum[t] : 0;
  s[t] = v;
  __syncthreads();
  for (int d = 1; d < 256; d <<= 1) {
    int x = (t >= d) ? s[t - d] : 0;
    __syncthreads();
    s[t] += x;
    __syncthreads();
  }
  if (t < nb) bsum[t] = s[t] - v;
  if (t == 255) bsum[nb] = s[255];
}
__global__ void scan3_k(int* __restrict__ off, const int* __restrict__ bsum, int n, int nb) {
  int gid = blockIdx.x * 256 + threadIdx.x;
  if (gid < n) off[gid] += bsum[gid >> 8];
  if (gid == 0) off[n] = bsum[nb];
}
__global__ void copy_i(const int* a, int* b, int n) {
  int i = blockIdx.x * blockDim.x + threadIdx.x;
  if (i < n) b[i] = a[i];
}
__global__ void fill_k(const int* __restrict__ src, const int* __restrict__ dst,
                       int* __restrict__ cursor, int* __restrict__ csr, int E, int n) {
  int e = blockIdx.x * blockDim.x + threadIdx.x;
  if (e < E) {
    int d = dst[e];
    if ((unsigned)d < (unsigned)n) {
      int p = atomicAdd(&cursor[d], 1);
      int s = src[e];
      if ((unsigned)s >= (unsigned)n) s = 0;
      csr[p] = s;
    }
  }
}

// ------- mean aggregation: one wave per node, int8 gather, int8 out -------
template <int K, int STRIDE>
__global__ __launch_bounds__(256) void agg_mean_i8w(char* __restrict__ cat,
                                                    const float* __restrict__ rscale,
                                                    const int* __restrict__ off,
                                                    const int* __restrict__ csr) {
  const int node = blockIdx.x * 4 + (threadIdx.x >> 6);
  const int lane = threadIdx.x & 63;
  const int d = lane * 16;
  const bool act = (d < K);
  const int e0 = off[node], e1 = off[node + 1];
  float a[16];
#pragma unroll
  for (int k = 0; k < 16; ++k) a[k] = 0.f;
  if (act) {
    const char* fp = cat + (size_t)K + d;  // feature half base + lane offset
    int e = e0;
    for (; e + 7 < e1; e += 8) {
      int s0 = csr[e],     s1 = csr[e + 1], s2 = csr[e + 2], s3 = csr[e + 3];
      int s4 = csr[e + 4], s5 = csr[e + 5], s6 = csr[e + 6], s7 = csr[e + 7];
      i8x16 v0 = *(const i8x16*)(fp + (size_t)s0 * STRIDE);
      i8x16 v1 = *(const i8x16*)(fp + (size_t)s1 * STRIDE);
      i8x16 v2 = *(const i8x16*)(fp + (size_t)s2 * STRIDE);
      i8x16 v3 = *(const i8x16*)(fp + (size_t)s3 * STRIDE);
      i8x16 v4 = *(const i8x16*)(fp + (size_t)s4 * STRIDE);
      i8x16 v5 = *(const i8x16*)(fp + (size_t)s5 * STRIDE);
      i8x16 v6 = *(const i8x16*)(fp + (size_t)s6 * STRIDE);
      i8x16 v7 = *(const i8x16*)(fp + (size_t)s7 * STRIDE);
      float c0 = rscale[s0], c1 = rscale[s1], c2 = rscale[s2], c3 = rscale[s3];
      float c4 = rscale[s4], c5 = rscale[s5], c6 = rscale[s6], c7 = rscale[s7];
#pragma unroll
      for (int k = 0; k < 16; ++k) {
        a[k] += c0 * (float)v0[k] + c1 * (float)v1[k] + c2 * (float)v2[k] + c3 * (float)v3[k];
        a[k] += c4 * (float)v4[k] + c5 * (float)v5[k] + c6 * (float)v6[k] + c7 * (float)v7[k];
      }
    }
    for (; e < e1; ++e) {
      int s = csr[e];
      float c = rscale[s];
      i8x16 v = *(const i8x16*)(fp + (size_t)s * STRIDE);
#pragma unroll
      for (int k = 0; k < 16; ++k) a[k] += c * (float)v[k];
    }
  }
  if (act) {
    int deg = e1 - e0;
    float inv = 1.f / (float)(deg > 1 ? deg : 1);
    float sc = rscale[node];
    float qi = sc > 0.f ? 1.f / sc : 0.f;  // quantize mean with row's own scale
    i8x16 q;
#pragma unroll
    for (int k = 0; k < 16; ++k) {
      float m = a[k] * inv * qi;
      m = fminf(fmaxf(rintf(m), -127.f), 127.f);
      q[k] = (char)(int)m;
    }
    *(i8x16*)&cat[(size_t)node * STRIDE + d] = q;  // mean half
  }
}

// ---------------- single-pass K-concatenated int8 MFMA GEMM ----------------
// C[m,n] = relu?( sA(m)*sW(n)*sum_k A[m,k]W[n,k] + bias[n] ), bf16 out.
// 256x128 tile, 8 waves (4M x 2N), 64x64 per wave, mfma_i32_16x16x64_i8.
// T1: bijective XCD block swizzle (A-panel reuse within one L2).
// T3+T4: double-buffered LDS + counted s_waitcnt vmcnt(3) across raw s_barrier.
// T2: conflict-free LDS read swizzle via pre-swizzled GLOBAL source chunk.
// T5: s_setprio(1) around the MFMA cluster.
// Read-drain placed AFTER the MFMA cluster: compiler interleaves ds_read
// completion (counted lgkmcnt) with early MFMAs; the trailing lgkmcnt(0) is
// free by then and guards buffer reuse across the end barrier.
// Epilogue stages C through LDS and stores full 256B row segments (no RMW).
template <int KP, int N, bool RELU>
__global__ __launch_bounds__(512, 4) void gemm_i8(const char* __restrict__ A,
                                                  const char* __restrict__ W,
                                                  const float* __restrict__ sA_,
                                                  const float* __restrict__ sW_,
                                                  const float* __restrict__ bias,
                                                  unsigned short* __restrict__ C) {
  // double buffer: [2][ A:16384 | B:8192 ] + scales (sc0:256, sc1:128)
  __shared__ __align__(16) char smem[50688];
  float* sc0 = (float*)(smem + 49152);
  float* sc1 = sc0 + 256;

  // bijective XCD swizzle: each XCD gets a contiguous chunk of work ids,
  // x (N-dim) fastest inside the chunk -> A-panel reuse within one L2.
  const int gx = gridDim.x;
  const int nwg = gx * gridDim.y;
  const int flat = blockIdx.y * gx + blockIdx.x;
  int newid = flat;
  if ((nwg & 7) == 0) newid = (flat & 7) * (nwg >> 3) + (flat >> 3);
  const int bxi = newid % gx;
  const int byi = newid / gx;

  const int tid = threadIdx.x;
  const int wave = tid >> 6, lane = tid & 63;
  const int quad = lane >> 4, l16 = lane & 15;
  const int wm = (wave >> 1) * 64, wn = (wave & 1) * 64;  // wm {0,64,128,192}, wn {0,64}
  const long long bm = (long long)byi * 256;
  const long long bn = (long long)bxi * 128;

  if (tid < 256) sc0[tid] = sA_[bm + tid];
  else if (tid < 384) sc1[tid - 256] = sW_[bn + tid - 256];

  // staging: thread t covers row t>>2 (A also +128), swizzled chunk
  const int srow = tid >> 2;                       // 0..127
  const int cswz = (tid & 3) ^ ((tid >> 3) & 3);   // = slot ^ ((row>>1)&3)
  const int ldst = tid * 16;
  const char* gA = A + (bm + srow) * (long long)KP + cswz * 16;
  const char* gW = W + (bn + srow) * (long long)KP + cswz * 16;

  // fragment-read sub-offset: slot = quad ^ ((l16>>1)&3)
  const int rdoff = (quad ^ ((l16 >> 1) & 3)) << 4;

  i32x4 iacc[4][4];
#pragma unroll
  for (int i = 0; i < 4; ++i)
#pragma unroll
    for (int j = 0; j < 4; ++j) iacc[i][j] = (i32x4){0, 0, 0, 0};

  constexpr int NT = KP / 64;

  // prologue: stage tile 0 into buffer 0 (A-lo, A-hi, B = 3 loads/wave)
  {
    char* d = smem + ldst;
    gl_lds16(gA, d);
    gl_lds16(gA + (size_t)128 * KP, d + 8192);
    gl_lds16(gW, d + 16384);
  }

#pragma unroll 1
  for (int t = 0; t < NT; ++t) {
    const int cur = t & 1;
    if (t + 1 < NT) {
      // stage next tile into alternate buffer (3 loads, left in flight)
      char* d = smem + (cur ^ 1) * 24576 + ldst;
      const char* sa = gA + (size_t)(t + 1) * 64;
      const char* sw = gW + (size_t)(t + 1) * 64;
      gl_lds16(sa, d);
      gl_lds16(sa + (size_t)128 * KP, d + 8192);
      gl_lds16(sw, d + 16384);
      asm volatile("s_waitcnt vmcnt(3)" ::: "memory");  // tile t landed; t+1 in flight
    } else {
      asm volatile("s_waitcnt vmcnt(0)" ::: "memory");  // drain last tile
    }
    __builtin_amdgcn_sched_barrier(0);
    __builtin_amdgcn_s_barrier();  // all waves' stage(t) visible
    __builtin_amdgcn_sched_barrier(0);

    const char* rb = smem + cur * 24576;
    i32x4 af[4], bg[4];
    // read order: af0, bg0..3, af1..3 -> first MFMA ready after 2 returns;
    // compiler inserts counted lgkmcnt so MFMAs overlap remaining reads.
    af[0] = *(const i32x4*)&rb[(wm + l16) * 64 + rdoff];
#pragma unroll
    for (int j = 0; j < 4; ++j)
      bg[j] = *(const i32x4*)&rb[16384 + (wn + 16 * j + l16) * 64 + rdoff];
#pragma unroll
    for (int i = 1; i < 4; ++i)
      af[i] = *(const i32x4*)&rb[(wm + 16 * i + l16) * 64 + rdoff];

    __builtin_amdgcn_s_setprio(1);
#pragma unroll
    for (int i = 0; i < 4; ++i)
#pragma unroll
      for (int j = 0; j < 4; ++j)
        iacc[i][j] = __builtin_amdgcn_mfma_i32_16x16x64_i8(af[i], bg[j], iacc[i][j], 0, 0, 0);
    __builtin_amdgcn_s_setprio(0);

    __builtin_amdgcn_sched_barrier(0);  // pin MFMAs (and their lgkm waits) above
    asm volatile("s_waitcnt lgkmcnt(0)" ::: "memory");  // buf[cur] reads all complete (free)
    __builtin_amdgcn_s_barrier();  // safe to overwrite buf[cur] next iteration
    __builtin_amdgcn_sched_barrier(0);
  }

  // ---- epilogue: scales/bias to regs, reuse smem[0..34816) as C tile ----
  __syncthreads();
  float rs[4][4], cs[4], bvj[4];
#pragma unroll
  for (int i = 0; i < 4; ++i)
#pragma unroll
    for (int r = 0; r < 4; ++r) rs[i][r] = sc0[wm + 16 * i + quad * 4 + r];
#pragma unroll
  for (int j = 0; j < 4; ++j) {
    const int coll = wn + 16 * j + l16;
    cs[j] = sc1[coll];
    bvj[j] = bias[bn + coll];
  }
  unsigned short* ct = (unsigned short*)smem;  // [128][136] u16 = 34816 B
  const int trow = tid >> 4;        // 0..31
  const int tcol = (tid & 15) * 8;  // u16 offset within row
#pragma unroll
  for (int p = 0; p < 2; ++p) {
    __syncthreads();
    if ((wm >> 7) == p) {
      const int lbase = wm - p * 128;
#pragma unroll
      for (int i = 0; i < 4; ++i)
#pragma unroll
        for (int j = 0; j < 4; ++j)
#pragma unroll
          for (int r = 0; r < 4; ++r) {
            float v = (float)iacc[i][j][r] * rs[i][r] * cs[j] + bvj[j];
            if (RELU) v = fmaxf(v, 0.f);
            ct[(lbase + 16 * i + quad * 4 + r) * 136 + wn + 16 * j + l16] = f2bf(v);
          }
    }
    __syncthreads();  // C half-tile staged
#pragma unroll
    for (int s = 0; s < 4; ++s) {
      const int rl = s * 32 + trow;
      i32x4 vv = *(const i32x4*)&ct[rl * 136 + tcol];
      *(i32x4*)&C[(bm + p * 128 + rl) * (long long)N + bn + tcol] = vv;
    }
  }
}

// ---------------- graph boundaries ----------------
__global__ void bounds_k(const int* __restrict__ batch, int* __restrict__ gstart, int n, int G) {
  int g = blockIdx.x * blockDim.x + threadIdx.x;
  if (g > G) return;
  int lo = 0, hi = n;
  while (lo < hi) {
    int mid = (lo + hi) >> 1;
    if (batch[mid] < g) lo = mid + 1; else hi = mid;
  }
  gstart[g] = lo;
}

// ---------------- segment max pool ----------------
__global__ void segmax_k(const unsigned short* __restrict__ h2b, const int* __restrict__ gstart,
                         float* __restrict__ pooled) {
  int g = blockIdx.x;
  int c = blockIdx.y * 256 + threadIdx.x;
  int i0 = gstart[g], i1 = gstart[g + 1];
  float m = -3.4e38f;
  for (int i = i0; i < i1; ++i) m = fmaxf(m, bf2f(h2b[(size_t)i * D2 + c]));
  if (i0 >= i1) m = 0.f;
  pooled[(size_t)g * D2 + c] = m;
}

// ---------------- MLP head (fp32) ----------------
__global__ void head1_k(const float* __restrict__ pooled, const float* __restrict__ Wf1,
                        const float* __restrict__ bf1, float* __restrict__ hid) {
  int g = blockIdx.x, chunk = blockIdx.y;
  __shared__ float sp[2048];
  for (int i = threadIdx.x; i < 2048; i += 256) sp[i] = pooled[(size_t)g * 2048 + i];
  __syncthreads();
  int wave = threadIdx.x >> 6, lane = threadIdx.x & 63;
  for (int oi = wave; oi < 64; oi += 4) {
    int o = chunk * 64 + oi;
    const float4* wr = (const float4*)&Wf1[(size_t)o * 2048];
    float s = 0.f;
    for (int c = lane; c < 512; c += 64) {
      float4 wv = wr[c];
      float4 pv = *(const float4*)&sp[c * 4];
      s += wv.x * pv.x + wv.y * pv.y + wv.z * pv.z + wv.w * pv.w;
    }
    for (int off = 32; off; off >>= 1) s += __shfl_down(s, off);
    if (lane == 0) hid[(size_t)g * 1024 + o] = fmaxf(s + bf1[o], 0.f);
  }
}
__global__ void head2_k(const float* __restrict__ hid, const float* __restrict__ Wf2,
                        const float* __restrict__ bf2, float* __restrict__ out) {
  int g = blockIdx.x, t = threadIdx.x;
  __shared__ float sh[1024];
  __shared__ float red[256];
  for (int i = t; i < 1024; i += 256) sh[i] = hid[(size_t)g * 1024 + i];
  __syncthreads();
  for (int o = 0; o < 6; ++o) {
    float s = 0.f;
    for (int k = t; k < 1024; k += 256) s += sh[k] * Wf2[o * 1024 + k];
    red[t] = s;
    __syncthreads();
    for (int d = 128; d; d >>= 1) {
      if (t < d) red[t] += red[t + d];
      __syncthreads();
    }
    if (t == 0) out[g * 6 + o] = red[0] + bf2[o];
    __syncthreads();
  }
}

extern "C" void kernel_launch(void* const* d_in, const int* in_sizes, int n_in,
                              void* d_out, int out_size, void* d_ws, size_t ws_size,
                              hipStream_t stream) {
  const float* x    = (const float*)d_in[0];
  const int* ei     = (const int*)d_in[1];
  const int* batch  = (const int*)d_in[2];
  const float* W1l  = (const float*)d_in[3];
  const float* b1   = (const float*)d_in[4];
  const float* W1r  = (const float*)d_in[5];
  const float* W2l  = (const float*)d_in[6];
  const float* b2   = (const float*)d_in[7];
  const float* W2r  = (const float*)d_in[8];
  const float* Wf1  = (const float*)d_in[9];
  const float* bf1  = (const float*)d_in[10];
  const float* Wf2  = (const float*)d_in[11];
  const float* bf2  = (const float*)d_in[12];
  float* out = (float*)d_out;

  const int E = in_sizes[1] / 2;
  const int* srcp = ei;
  const int* dstp = ei + E;
  const int NB = (MP + 255) / 256;  // scan blocks

  char* w = (char*)d_ws;
  auto take = [&](size_t b) {
    void* p = (void*)w;
    w += (b + 255) & ~(size_t)255;
    return p;
  };
  char* cat1      = (char*)take((size_t)MP * KC1);        // [mean | x] int8
  char* cat2      = (char*)take((size_t)MP * KC2);        // [mean2 | h1] int8
  unsigned short* h1b = (unsigned short*)take((size_t)MP * D1 * 2);
  unsigned short* h2b = (unsigned short*)take((size_t)MP * D2 * 2);
  char* wcat1     = (char*)take((size_t)D1 * KC1);
  char* wcat2     = (char*)take((size_t)D2 * KC2);
  float* xscale   = (float*)take((size_t)MP * 4);
  float* h1scale  = (float*)take((size_t)MP * 4);
  float* swc1     = (float*)take((size_t)D1 * 4);
  float* swc2     = (float*)take((size_t)D2 * 4);
  int* deg    = (int*)take((size_t)MP * 4);
  int* off    = (int*)take((size_t)(MP + 1) * 4);
  int* bsum   = (int*)take((size_t)(NB + 1) * 4);
  int* cursor = (int*)take((size_t)MP * 4);
  int* csr    = (int*)take((size_t)E * 4);
  int* gstart = (int*)take((size_t)(NG + 1) * 4);
  float* pooled = (float*)take((size_t)NG * D2 * 4);
  float* hid    = (float*)take((size_t)NG * 1024 * 4);

  cvt_x<<<MP, 256, 0, stream>>>(x, cat1, xscale);
  wq_cat<<<D1, 256, 0, stream>>>(W1l, W1r, D0, K0, wcat1, swc1);
  wq_cat<<<D2, 256, 0, stream>>>(W2l, W2r, D1, D1, wcat2, swc2);

  zero_i<<<(MP + 255) / 256, 256, 0, stream>>>(deg, MP);
  count_k<<<(E + 255) / 256, 256, 0, stream>>>(dstp, deg, E, NN);
  scan1_k<<<NB, 256, 0, stream>>>(deg, off, bsum, MP);
  scan2_k<<<1, 256, 0, stream>>>(bsum, NB);
  scan3_k<<<NB, 256, 0, stream>>>(off, bsum, MP, NB);
  copy_i<<<(MP + 255) / 256, 256, 0, stream>>>(off, cursor, MP);
  fill_k<<<(E + 255) / 256, 256, 0, stream>>>(srcp, dstp, cursor, csr, E, NN);

  // conv1: mean half of cat1 <- agg(x half); h1 = relu(cat1 @ wcat1^T + b1)
  agg_mean_i8w<K0, KC1><<<MP / 4, 256, 0, stream>>>(cat1, xscale, off, csr);
  gemm_i8<KC1, D1, true><<<dim3(D1 / 128, MP / 256), 512, 0, stream>>>(
      cat1, wcat1, xscale, swc1, b1, h1b);

  // conv2: quantize h1 into cat2; mean2 half <- agg(h1 half); h2 = cat2 @ wcat2^T + b2
  quant_rows<<<MP, 256, 0, stream>>>(h1b, cat2, h1scale);
  agg_mean_i8w<D1, KC2><<<MP / 4, 256, 0, stream>>>(cat2, h1scale, off, csr);
  gemm_i8<KC2, D2, false><<<dim3(D2 / 128, MP / 256), 512, 0, stream>>>(
      cat2, wcat2, h1scale, swc2, b2, h2b);

  bounds_k<<<1, 128, 0, stream>>>(batch, gstart, NN, NG);
  segmax_k<<<dim3(NG, D2 / 256), 256, 0, stream>>>(h2b, gstart, pooled);
  head1_k<<<dim3(NG, 16), 256, 0, stream>>>(pooled, Wf1, bf1, hid);
  head2_k<<<NG, 256, 0, stream>>>(hid, Wf2, bf2, out);
}